// Round 17
// baseline (11525.906 us; speedup 1.0000x reference)
//
#include <hip/hip_runtime.h>
#include <stdint.h>

#define DEVINL __device__ __forceinline__

typedef __attribute__((ext_vector_type(8))) _Float16 half8;
typedef __attribute__((ext_vector_type(4))) _Float16 half4;
typedef __attribute__((ext_vector_type(4))) float f32x4;

typedef __attribute__((address_space(1))) void* gas_ptr;
typedef __attribute__((address_space(3))) void* las_ptr;

DEVINL void g2l16(const void* g, void* l) {
    __builtin_amdgcn_global_load_lds((gas_ptr)g, (las_ptr)l, 16, 0, 0);
}

// ---------------------------------------------------------------- utilities

__global__ void init_kernel(unsigned* u) {
    if (threadIdx.x < 16) u[threadIdx.x] = 0u;
}

__global__ void sentinel_kernel(float* out) { out[0] = 1.0e9f; }

// absmax of x + the 3 weight tensors in one launch; blockIdx.y selects tensor.
__global__ void absmax4_kernel(const float* __restrict__ x,
                               const float* __restrict__ w0,
                               const float* __restrict__ w1,
                               const float* __restrict__ w2,
                               unsigned* __restrict__ out) {
    const float* src; int n4;
    if (blockIdx.y == 0)      { src = x;  n4 = 8388608; }
    else if (blockIdx.y == 1) { src = w0; n4 = 11272192; }
    else if (blockIdx.y == 2) { src = w1; n4 = 11272192; }
    else                      { src = w2; n4 = 11272192; }
    int i = blockIdx.x * blockDim.x + threadIdx.x;
    const int stride = gridDim.x * blockDim.x;
    float m = 0.0f;
    const float4* s4 = (const float4*)src;
    for (; i < n4; i += stride) {
        float4 v = s4[i];
        m = fmaxf(m, fmaxf(fmaxf(fabsf(v.x), fabsf(v.y)),
                           fmaxf(fabsf(v.z), fabsf(v.w))));
    }
    #pragma unroll
    for (int off = 32; off > 0; off >>= 1) m = fmaxf(m, __shfl_down(m, off));
    if ((threadIdx.x & 63) == 0) atomicMax(out + blockIdx.y, __float_as_uint(m));
}

__global__ void convert_f16_kernel(const float* __restrict__ src, int n4,
                                   _Float16* __restrict__ dst) {
    int i = blockIdx.x * blockDim.x + threadIdx.x;
    const int stride = gridDim.x * blockDim.x;
    const float4* s4 = (const float4*)src;
    half4* d4 = (half4*)dst;
    for (; i < n4; i += stride) {
        float4 v = s4[i];
        half4 h;
        h.x = (_Float16)v.x; h.y = (_Float16)v.y;
        h.z = (_Float16)v.z; h.w = (_Float16)v.w;
        d4[i] = h;
    }
}

__global__ void transpose_f16_kernel(const float* __restrict__ src, int rows, int cols,
                                     _Float16* __restrict__ dst) {
    long i = (long)blockIdx.x * blockDim.x + threadIdx.x;
    if (i < (long)rows * cols) {
        int r = (int)(i / cols), c = (int)(i % cols);
        dst[(long)c * rows + r] = (_Float16)src[i];
    }
}

// ---------------------------------------------------------------- quantization (fp64)

DEVINL double lvl64(double aa) {
    if      (aa >= 5.0)  return 6.0;
    else if (aa >= 3.5)  return 4.0;
    else if (aa >= 2.5)  return 3.0;
    else if (aa >= 1.75) return 2.0;
    else if (aa >= 1.25) return 1.5;
    else if (aa >= 0.75) return 1.0;
    else if (aa >= 0.25) return 0.5;
    return 0.0;
}

// per-row gather+quantize -> fp16 hi + fp16 mid (identical math to green rounds)
DEVINL void quant_split_row(const float* __restrict__ srow,
                            _Float16* __restrict__ hrow, _Float16* __restrict__ mrow,
                            int nb, int nq, const int* __restrict__ idx, double s,
                            int tid, int nthr) {
    for (int j = tid; j < nb; j += nthr) {
        const int* ip = idx + (j << 4);
        double v[16];
        #pragma unroll
        for (int i = 0; i < 16; ++i) v[i] = (double)srow[ip[i]];
        if (j < nq) {
            double t[16];
            #pragma unroll
            for (int i = 0; i < 16; ++i) t[i] = v[i] / s;
            double bmax = 0.0;
            #pragma unroll
            for (int i = 0; i < 16; ++i) bmax = fmax(bmax, fabs(t[i]));
            double sb = fmin(fmax(bmax / 6.0, 1e-12), 448.0);
            #pragma unroll
            for (int i = 0; i < 16; ++i) {
                double a = t[i] / sb;
                v[i] = (copysign(lvl64(fabs(a)), a) * sb) * s;
            }
        }
        _Float16 h[16], m[16];
        #pragma unroll
        for (int i = 0; i < 16; ++i) {
            _Float16 hi = (_Float16)(float)v[i];
            double r = v[i] - (double)(float)hi;
            h[i] = hi;
            m[i] = (_Float16)(float)(r * 4096.0);
        }
        *(half8*)(hrow + (j << 4))     = *(half8*)&h[0];
        *(half8*)(hrow + (j << 4) + 8) = *(half8*)&h[8];
        *(half8*)(mrow + (j << 4))     = *(half8*)&m[0];
        *(half8*)(mrow + (j << 4) + 8) = *(half8*)&m[8];
    }
}

__global__ void quant_split16_kernel(const float* __restrict__ src, int D, int nb, int nq,
                                     const int* __restrict__ idx,
                                     const unsigned* __restrict__ smax_bits,
                                     _Float16* __restrict__ dhi,
                                     _Float16* __restrict__ dmid) {
    double s = fmax((double)__uint_as_float(*smax_bits) / 2688.0, 1e-12);
    quant_split_row(src + (long)blockIdx.x * D,
                    dhi + (long)blockIdx.x * D, dmid + (long)blockIdx.x * D,
                    nb, nq, idx, s, threadIdx.x, blockDim.x);
}

// merged wg+wu chunk quantization: grid = 2*nrows; first half wg, second half wu.
__global__ void quant_wgu_kernel(const float* __restrict__ wg, const float* __restrict__ wu,
                                 int nrows, const int* __restrict__ idx,
                                 const unsigned* __restrict__ sg_bits,
                                 const unsigned* __restrict__ su_bits,
                                 _Float16* __restrict__ wgh, _Float16* __restrict__ wgm,
                                 _Float16* __restrict__ wuh, _Float16* __restrict__ wum) {
    const bool isU = (int)blockIdx.x >= nrows;
    const int r = isU ? (blockIdx.x - nrows) : blockIdx.x;
    const float* src = (isU ? wu : wg) + (long)r * 4096;
    _Float16* dh = (isU ? wuh : wgh) + (long)r * 4096;
    _Float16* dm = (isU ? wum : wgm) + (long)r * 4096;
    double s = fmax((double)__uint_as_float(isU ? *su_bits : *sg_bits) / 2688.0, 1e-12);
    quant_split_row(src, dh, dm, 256, 248, idx, s, threadIdx.x, blockDim.x);
}

__global__ void quant_rows_kernel(const float* __restrict__ src, int D, int nb, int nq,
                                  const int* __restrict__ idx,
                                  const unsigned* __restrict__ smax_bits,
                                  _Float16* __restrict__ dst) {
    const float* srow = src + (long)blockIdx.x * D;
    _Float16* drow = dst + (long)blockIdx.x * D;
    double s = fmax((double)__uint_as_float(*smax_bits) / 2688.0, 1e-12);
    for (int j = threadIdx.x; j < nb; j += blockDim.x) {
        const int* ip = idx + (j << 4);
        double v[16];
        #pragma unroll
        for (int i = 0; i < 16; ++i) v[i] = (double)srow[ip[i]];
        _Float16 o[16];
        if (j >= nq) {
            #pragma unroll
            for (int i = 0; i < 16; ++i) o[i] = (_Float16)(float)v[i];
        } else {
            double t[16];
            #pragma unroll
            for (int i = 0; i < 16; ++i) t[i] = v[i] / s;
            double bmax = 0.0;
            #pragma unroll
            for (int i = 0; i < 16; ++i) bmax = fmax(bmax, fabs(t[i]));
            double sb = fmin(fmax(bmax / 6.0, 1e-12), 448.0);
            #pragma unroll
            for (int i = 0; i < 16; ++i) {
                double a = t[i] / sb;
                o[i] = (_Float16)(float)((copysign(lvl64(fabs(a)), a) * sb) * s);
            }
        }
        *(half8*)(drow + (j << 4))     = *(half8*)&o[0];
        *(half8*)(drow + (j << 4) + 8) = *(half8*)&o[8];
    }
}

// tree-variant (tiers 0/1): in-place overlay, ordered by the launcher's tree
__global__ void requant_h_kernel(float* __restrict__ H, int rowbase,
                                 const int* __restrict__ idx,
                                 const unsigned long long* __restrict__ hmax_bits) {
    __shared__ __align__(16) _Float16 buf[11008];
    const int r = rowbase + blockIdx.x;
    const float* srow = H + (long)r * 11008;
    _Float16* drow = (_Float16*)((char*)H + 180355072L) + (long)r * 11008;
    double s = fmax(__longlong_as_double((long long)*hmax_bits) / 2688.0, 1e-12);
    for (int j = threadIdx.x; j < 688; j += blockDim.x) {
        const int* ip = idx + (j << 4);
        double v[16];
        #pragma unroll
        for (int i = 0; i < 16; ++i) v[i] = (double)srow[ip[i]];
        if (j < 680) {
            double t[16];
            #pragma unroll
            for (int i = 0; i < 16; ++i) t[i] = v[i] / s;
            double bmax = 0.0;
            #pragma unroll
            for (int i = 0; i < 16; ++i) bmax = fmax(bmax, fabs(t[i]));
            double sb = fmin(fmax(bmax / 6.0, 1e-12), 448.0);
            #pragma unroll
            for (int i = 0; i < 16; ++i) {
                double a = t[i] / sb;
                v[i] = (copysign(lvl64(fabs(a)), a) * sb) * s;
            }
        }
        #pragma unroll
        for (int i = 0; i < 16; ++i) buf[(j << 4) + i] = (_Float16)(float)v[i];
    }
    __syncthreads();
    uint4* dst4 = (uint4*)drow;
    const uint4* src4 = (const uint4*)buf;
    for (int e = threadIdx.x; e < (11008 * 2) / 16; e += blockDim.x) dst4[e] = src4[e];
}

// direct-variant (tier 2): dst is a disjoint region -> single unordered launch.
__global__ void requant_h_direct_kernel(const float* __restrict__ H,
                                        _Float16* __restrict__ dst,
                                        const int* __restrict__ idx,
                                        const unsigned long long* __restrict__ hmax_bits) {
    const int r = blockIdx.x;
    const float* srow = H + (long)r * 11008;
    _Float16* drow = dst + (long)r * 11008;
    double s = fmax(__longlong_as_double((long long)*hmax_bits) / 2688.0, 1e-12);
    for (int j = threadIdx.x; j < 688; j += blockDim.x) {
        const int* ip = idx + (j << 4);
        double v[16];
        #pragma unroll
        for (int i = 0; i < 16; ++i) v[i] = (double)srow[ip[i]];
        if (j < 680) {
            double t[16];
            #pragma unroll
            for (int i = 0; i < 16; ++i) t[i] = v[i] / s;
            double bmax = 0.0;
            #pragma unroll
            for (int i = 0; i < 16; ++i) bmax = fmax(bmax, fabs(t[i]));
            double sb = fmin(fmax(bmax / 6.0, 1e-12), 448.0);
            #pragma unroll
            for (int i = 0; i < 16; ++i) {
                double a = t[i] / sb;
                v[i] = (copysign(lvl64(fabs(a)), a) * sb) * s;
            }
        }
        _Float16 o[16];
        #pragma unroll
        for (int i = 0; i < 16; ++i) o[i] = (_Float16)(float)v[i];
        *(half8*)(drow + (j << 4))     = *(half8*)&o[0];
        *(half8*)(drow + (j << 4) + 8) = *(half8*)&o[8];
    }
}

// ---------------------------------------------------------------- GEMM 1
// fp16-split GEMM, fp64 chunk-flushed accumulation. Per-element math bit-identical
// to all green rounds (same 32x32 wave-tile fragments, same ascending-k order,
// flush every K=512). NEW decomposition: 128(M)x64(N) tile, 512 thr (8 waves
// 4x2, wave-tile 32x32 -> identical per-lane registers, VGPR ~112), single
// 64KB LDS buffer, 2 blocks/CU (16 waves/CU). B restaged half as often:
// total staged volume 69 -> 46 GB.

__global__ __launch_bounds__(512, 4)
void gemm1_kernel(const _Float16* __restrict__ Ah, const _Float16* __restrict__ Am,
                  const _Float16* __restrict__ Bgh, const _Float16* __restrict__ Bgm,
                  const _Float16* __restrict__ Buh, const _Float16* __restrict__ Bum,
                  float* __restrict__ H, int hrow0, int hcol0,
                  unsigned long long* __restrict__ hmax64) {
    __shared__ __align__(16) _Float16 sAh[8192], sAm[8192];            // 128x64 each
    __shared__ __align__(16) _Float16 sgh[4096], sgm[4096];            // 64x64 each
    __shared__ __align__(16) _Float16 suh[4096], sum_[4096];           // total 64KB
    const int tid = threadIdx.x;
    const int lane = tid & 63, wave = tid >> 6;
    const int wr = wave >> 1, wc = wave & 1;          // 4x2 wave grid
    const int arow0 = blockIdx.x * 128, brow0 = blockIdx.y * 64;

    if ((blockIdx.x ^ blockIdx.y) & 1) __builtin_amdgcn_s_sleep(32);

    // staging: thread t -> row t>>3 (0..63), slot t&7; src slot = sl^(row&7);
    // row&7 invariant under +64 (A pass 2 covers rows 64..127).
    const int r0 = tid >> 3, sl = tid & 7;
    const int slx = sl ^ (r0 & 7);
    const _Float16* gAh = Ah  + (long)(arow0 + r0) * 4096 + slx * 8;
    const _Float16* gAm = Am  + (long)(arow0 + r0) * 4096 + slx * 8;
    const _Float16* ggh = Bgh + (long)(brow0 + r0) * 4096 + slx * 8;
    const _Float16* ggm = Bgm + (long)(brow0 + r0) * 4096 + slx * 8;
    const _Float16* guh = Buh + (long)(brow0 + r0) * 4096 + slx * 8;
    const _Float16* gum = Bum + (long)(brow0 + r0) * 4096 + slx * 8;
    const int wo = wave * 512;            // wave-uniform LDS base (elements)
    const long R64 = 64L * 4096;          // +64 rows in source (A pass 2)

#define STAGE1(K0) do { \
        g2l16(gAh + (K0),       sAh + wo); \
        g2l16(gAh + (K0) + R64, sAh + 4096 + wo); \
        g2l16(gAm + (K0),       sAm + wo); \
        g2l16(gAm + (K0) + R64, sAm + 4096 + wo); \
        g2l16(ggh + (K0),       sgh + wo); \
        g2l16(ggm + (K0),       sgm + wo); \
        g2l16(guh + (K0),       suh + wo); \
        g2l16(gum + (K0),       sum_ + wo); \
    } while (0)

    const f32x4 z4 = {0.f, 0.f, 0.f, 0.f};
    f32x4 accg[2][2], accu[2][2], accgX[2][2], accuX[2][2];
    double accgD[2][2][4], accuD[2][2][4];
    #pragma unroll
    for (int i = 0; i < 2; ++i)
        #pragma unroll
        for (int j = 0; j < 2; ++j) {
            accg[i][j] = z4; accu[i][j] = z4; accgX[i][j] = z4; accuX[i][j] = z4;
            #pragma unroll
            for (int r = 0; r < 4; ++r) { accgD[i][j][r] = 0.0; accuD[i][j][r] = 0.0; }
        }

    const int frow = lane & 15;
    const int l4 = lane >> 4;

    for (int t = 0; t < 64; ++t) {
        STAGE1(t << 6);
        __syncthreads();
        __builtin_amdgcn_s_setprio(1);
        #pragma unroll
        for (int kk = 0; kk < 2; ++kk) {
            const int ksl = (kk << 2) + l4;
            half8 ah[2], am2[2], bh[2], bm[2], ch[2], cm[2];
            #pragma unroll
            for (int i = 0; i < 2; ++i) {
                const int ra = wr * 32 + i * 16 + frow;    // 0..127
                const int so = (ksl ^ (ra & 7)) * 8;
                ah[i]  = *(const half8*)(sAh + ra * 64 + so);
                am2[i] = *(const half8*)(sAm + ra * 64 + so);
            }
            #pragma unroll
            for (int j = 0; j < 2; ++j) {
                const int rb = wc * 32 + j * 16 + frow;    // 0..63
                const int so = (ksl ^ (rb & 7)) * 8;
                bh[j] = *(const half8*)(sgh + rb * 64 + so);
                bm[j] = *(const half8*)(sgm + rb * 64 + so);
                ch[j] = *(const half8*)(suh + rb * 64 + so);
                cm[j] = *(const half8*)(sum_ + rb * 64 + so);
            }
            #pragma unroll
            for (int i = 0; i < 2; ++i)
                #pragma unroll
                for (int j = 0; j < 2; ++j) {
                    accg[i][j]  = __builtin_amdgcn_mfma_f32_16x16x32_f16(ah[i],  bh[j], accg[i][j], 0, 0, 0);
                    accgX[i][j] = __builtin_amdgcn_mfma_f32_16x16x32_f16(ah[i],  bm[j], accgX[i][j], 0, 0, 0);
                    accgX[i][j] = __builtin_amdgcn_mfma_f32_16x16x32_f16(am2[i], bh[j], accgX[i][j], 0, 0, 0);
                    accu[i][j]  = __builtin_amdgcn_mfma_f32_16x16x32_f16(ah[i],  ch[j], accu[i][j], 0, 0, 0);
                    accuX[i][j] = __builtin_amdgcn_mfma_f32_16x16x32_f16(ah[i],  cm[j], accuX[i][j], 0, 0, 0);
                    accuX[i][j] = __builtin_amdgcn_mfma_f32_16x16x32_f16(am2[i], ch[j], accuX[i][j], 0, 0, 0);
                }
        }
        __builtin_amdgcn_s_setprio(0);
        if ((t & 7) == 7) {   // flush every K=512 (cadence identical to green rounds)
            #pragma unroll
            for (int i = 0; i < 2; ++i)
                #pragma unroll
                for (int j = 0; j < 2; ++j) {
                    #pragma unroll
                    for (int r = 0; r < 4; ++r) {
                        accgD[i][j][r] += (double)accg[i][j][r];
                        accuD[i][j][r] += (double)accu[i][j][r];
                    }
                    accg[i][j] = z4; accu[i][j] = z4;
                }
        }
        __syncthreads();
    }
#undef STAGE1

    double lmax = 0.0;
    const int crow = l4 * 4, ccol = lane & 15;
    #pragma unroll
    for (int i = 0; i < 2; ++i) {
        #pragma unroll
        for (int j = 0; j < 2; ++j) {
            const int row = hrow0 + arow0 + wr * 32 + i * 16 + crow;
            const int col = hcol0 + brow0 + wc * 32 + j * 16 + ccol;
            #pragma unroll
            for (int r = 0; r < 4; ++r) {
                double g = accgD[i][j][r] + (double)accgX[i][j][r] * 0x1p-12;
                double u = accuD[i][j][r] + (double)accuX[i][j][r] * 0x1p-12;
                double sig = 1.0 / (1.0 + exp(-g));
                double h = (g * sig) * u;
                lmax = fmax(lmax, fabs(h));
                H[(long)(row + r) * 11008 + col] = (float)h;
            }
        }
    }
    #pragma unroll
    for (int off = 32; off > 0; off >>= 1) lmax = fmax(lmax, __shfl_down(lmax, off));
    if (lane == 0) atomicMax(hmax64, (unsigned long long)__double_as_longlong(lmax));
}

// ---------------------------------------------------------------- GEMM 2
// fp16, 128x128 tile, BK=128, 16-slot row swizzle (proven ~790us, at its
// staging-volume roofline); out = (Hq @ Wd^T)*scale + T1 @ lrB

__global__ __launch_bounds__(256, 2)
void gemm2_kernel(const _Float16* __restrict__ A,    // hq  [8192][11008]
                  const _Float16* __restrict__ B,    // wdq [4096][11008]
                  const float* __restrict__ scale,   // [4096]
                  const _Float16* __restrict__ T1,   // [8192][64]
                  const _Float16* __restrict__ BT,   // lrBT [4096][64]
                  float* __restrict__ out) {
    __shared__ __align__(16) _Float16 sA[128 * 128];   // 32 KB
    __shared__ __align__(16) _Float16 sB[128 * 128];   // 32 KB
    const int tid = threadIdx.x;
    const int lane = tid & 63, wave = tid >> 6;
    const int wr = wave >> 1, wc = wave & 1;
    const int arow0 = blockIdx.x * 128, brow0 = blockIdx.y * 128;

    const int qrow = tid >> 4, qsl = tid & 15;
    const int qslx = qsl ^ (qrow & 15);
    const _Float16* gA = A + (long)(arow0 + qrow) * 11008 + qslx * 8;
    const _Float16* gB = B + (long)(brow0 + qrow) * 11008 + qslx * 8;
    const long QROW16 = 16L * 11008;

    const f32x4 z4 = {0.f, 0.f, 0.f, 0.f};
    f32x4 acc[4][4];
    #pragma unroll
    for (int i = 0; i < 4; ++i)
        #pragma unroll
        for (int j = 0; j < 4; ++j) acc[i][j] = z4;

    const int frow = lane & 15;
    const int l4 = lane >> 4;

    for (int k0 = 0; k0 < 11008; k0 += 128) {
        #pragma unroll
        for (int q = 0; q < 8; ++q) {
            g2l16(gA + k0 + q * QROW16, sA + q * 2048 + wave * 512);
            g2l16(gB + k0 + q * QROW16, sB + q * 2048 + wave * 512);
        }
        __syncthreads();
        #pragma unroll
        for (int kk = 0; kk < 4; ++kk) {
            const int ksl = (kk << 2) + l4;
            half8 af[4], bf[4];
            #pragma unroll
            for (int i = 0; i < 4; ++i) {
                const int ra = wr * 64 + i * 16 + frow;
                af[i] = *(const half8*)(sA + ra * 128 + ((ksl ^ (ra & 15)) * 8));
            }
            #pragma unroll
            for (int j = 0; j < 4; ++j) {
                const int rb = wc * 64 + j * 16 + frow;
                bf[j] = *(const half8*)(sB + rb * 128 + ((ksl ^ (rb & 15)) * 8));
            }
            #pragma unroll
            for (int i = 0; i < 4; ++i)
                #pragma unroll
                for (int j = 0; j < 4; ++j)
                    acc[i][j] = __builtin_amdgcn_mfma_f32_16x16x32_f16(af[i], bf[j], acc[i][j], 0, 0, 0);
        }
        __syncthreads();
    }

    // rank-64 low-rank tail (separate accumulator; scale must not apply to it)
    f32x4 accL[4][4];
    #pragma unroll
    for (int i = 0; i < 4; ++i)
        #pragma unroll
        for (int j = 0; j < 4; ++j) accL[i][j] = z4;
    const int r8 = tid >> 3, sl8 = tid & 7;
    const int slx8 = sl8 ^ (r8 & 7);
    const _Float16* gT = T1 + (long)(arow0 + r8) * 64 + slx8 * 8;
    const _Float16* gL = BT + (long)(brow0 + r8) * 64 + slx8 * 8;
    #pragma unroll
    for (int q = 0; q < 4; ++q) {
        g2l16(gT + q * (32L * 64), sA + q * 2048 + wave * 512);
        g2l16(gL + q * (32L * 64), sB + q * 2048 + wave * 512);
    }
    __syncthreads();
    #pragma unroll
    for (int kk = 0; kk < 2; ++kk) {
        const int ksl = (kk << 2) + l4;
        half8 af[4], bf[4];
        #pragma unroll
        for (int i = 0; i < 4; ++i) {
            const int ra = wr * 64 + i * 16 + frow;
            af[i] = *(const half8*)(sA + ra * 64 + (ksl ^ (ra & 7)) * 8);
        }
        #pragma unroll
        for (int j = 0; j < 4; ++j) {
            const int rb = wc * 64 + j * 16 + frow;
            bf[j] = *(const half8*)(sB + rb * 64 + (ksl ^ (rb & 7)) * 8);
        }
        #pragma unroll
        for (int i = 0; i < 4; ++i)
            #pragma unroll
            for (int j = 0; j < 4; ++j)
                accL[i][j] = __builtin_amdgcn_mfma_f32_16x16x32_f16(af[i], bf[j], accL[i][j], 0, 0, 0);
    }

    const int crow = l4 * 4, ccol = lane & 15;
    #pragma unroll
    for (int j = 0; j < 4; ++j) {
        const int col = brow0 + wc * 64 + j * 16 + ccol;
        const float sc = scale[col];
        #pragma unroll
        for (int i = 0; i < 4; ++i) {
            const int row = arow0 + wr * 64 + i * 16 + crow;
            #pragma unroll
            for (int r = 0; r < 4; ++r)
                out[(long)(row + r) * 4096 + col] = acc[i][j][r] * sc + accL[i][j][r];
        }
    }
}

// T1 = xh @ lrA  (M=8192, N=64, K=4096), fp16. (tiny; unchanged)
__global__ __launch_bounds__(256, 2)
void lr1_kernel(const _Float16* __restrict__ X,
                const _Float16* __restrict__ AT,
                _Float16* __restrict__ T1) {
    __shared__ __align__(16) _Float16 sA[128 * 32];
    __shared__ __align__(16) _Float16 sB[64 * 32];
    const int tid = threadIdx.x;
    const int lane = tid & 63, wave = tid >> 6;
    const int arow0 = blockIdx.x * 128;

    const int rs = tid >> 2, cs8 = (tid & 3) * 8;
    const _Float16* gA = X + (long)(arow0 + rs) * 4096 + cs8;
    const _Float16* gB = AT + (long)rs * 4096 + cs8;
    _Float16* lA = sA + wave * 512;
    _Float16* lB = sB + wave * 512;

    const f32x4 z4 = {0.f, 0.f, 0.f, 0.f};
    f32x4 acc[2][4];
    #pragma unroll
    for (int i = 0; i < 2; ++i)
        #pragma unroll
        for (int j = 0; j < 4; ++j) acc[i][j] = z4;

    const int frow = lane & 15;
    const int fke = (lane >> 4) * 8;

    for (int k0 = 0; k0 < 4096; k0 += 32) {
        g2l16(gA + k0,             lA);
        g2l16(gA + k0 + 64 * 4096, lA + 2048);
        g2l16(gB + k0, lB);
        __syncthreads();
        half8 af[2], bf[4];
        #pragma unroll
        for (int i = 0; i < 2; ++i)
            af[i] = *(const half8*)(sA + (wave * 32 + i * 16 + frow) * 32 + fke);
        #pragma unroll
        for (int j = 0; j < 4; ++j)
            bf[j] = *(const half8*)(sB + (j * 16 + frow) * 32 + fke);
        #pragma unroll
        for (int i = 0; i < 2; ++i)
            #pragma unroll
            for (int j = 0; j < 4; ++j)
                acc[i][j] = __builtin_amdgcn_mfma_f32_16x16x32_f16(af[i], bf[j], acc[i][j], 0, 0, 0);
        __syncthreads();
    }

    const int crow = (lane >> 4) * 4, ccol = lane & 15;
    #pragma unroll
    for (int i = 0; i < 2; ++i)
        #pragma unroll
        for (int j = 0; j < 4; ++j) {
            const int row = arow0 + wave * 32 + i * 16 + crow;
            const int col = j * 16 + ccol;
            #pragma unroll
            for (int r = 0; r < 4; ++r)
                T1[(long)(row + r) * 64 + col] = (_Float16)acc[i][j][r];
        }
}

// ---------------------------------------------------------------- launch

extern "C" void kernel_launch(void* const* d_in, const int* in_sizes, int n_in,
                              void* d_out, int out_size, void* d_ws, size_t ws_size,
                              hipStream_t stream) {
    const float* x     = (const float*)d_in[0];
    const float* wg    = (const float*)d_in[1];
    const float* wu    = (const float*)d_in[2];
    const float* wd    = (const float*)d_in[3];
    const float* scale = (const float*)d_in[4];
    const float* lrA   = (const float*)d_in[5];
    const float* lrB   = (const float*)d_in[6];
    const int* upidx   = (const int*)d_in[7];
    const int* dnidx   = (const int*)d_in[8];
    float* out = (float*)d_out;
    char* ws = (char*)d_ws;

    // FALLBACK (proven r13): m-chunks 2048, f-chunks 1024. 427,819,264 B.
    const long F_XQH = 256;
    const long F_XQM = F_XQH + 16777216L;
    const long F_WGH = F_XQM + 16777216L;
    const long F_WGM = F_WGH + 8388608L;
    const long F_WUH = F_WGM + 8388608L;
    const long F_WUM = F_WUH + 8388608L;
    const long F_H   = F_WUM + 8388608L;
    const long NEED_FB = F_H + 360710144L;

    // BIG (proven r14): m-chunks 4096, f-chunks 2048. 494,928,128 B.
    const long B_XQH = 256;
    const long B_XQM = B_XQH + 33554432L;
    const long B_WGH = B_XQM + 33554432L;
    const long B_WGM = B_WGH + 16777216L;
    const long B_WUH = B_WGM + 16777216L;
    const long B_WUM = B_WUH + 16777216L;
    const long B_H   = B_WUM + 16777216L;
    const long NEED_BIG = B_H + 360710144L;

    // HUGE (proven r15/16): full 8192-row xq, f-chunks 2048. 562,036,992 B.
    const long G_XQH = 256;
    const long G_XQM = G_XQH + 67108864L;
    const long G_WGH = G_XQM + 67108864L;
    const long G_WGM = G_WGH + 16777216L;
    const long G_WUH = G_WGM + 16777216L;
    const long G_WUM = G_WUH + 16777216L;
    const long G_H   = G_WUM + 16777216L;
    const long NEED_HUGE = G_H + 360710144L;

    if (ws_size < (size_t)NEED_FB) { sentinel_kernel<<<1, 1, 0, stream>>>(out); return; }
    const int TIER = (ws_size >= (size_t)NEED_HUGE) ? 2
                   : (ws_size >= (size_t)NEED_BIG) ? 1 : 0;

    const long OFF_H = (TIER == 2) ? G_H : (TIER == 1) ? B_H : F_H;
    const long OFF_HQ   = OFF_H + 180355072L;
    const long OFF_WDQ  = OFF_H;
    const long OFF_XH   = OFF_H + 90177536L;
    const long OFF_T1   = OFF_XH + 67108864L;
    const long OFF_LRAT = OFF_T1 + 1048576L;
    const long OFF_LRBT = OFF_LRAT + 524288L;

    unsigned* sc = (unsigned*)ws;
    unsigned long long* hmax64 = (unsigned long long*)(ws + 32);
    _Float16* xqh = (_Float16*)(ws + ((TIER == 2) ? G_XQH : (TIER == 1) ? B_XQH : F_XQH));
    _Float16* xqm = (_Float16*)(ws + ((TIER == 2) ? G_XQM : (TIER == 1) ? B_XQM : F_XQM));
    _Float16* wgh = (_Float16*)(ws + ((TIER == 2) ? G_WGH : (TIER == 1) ? B_WGH : F_WGH));
    _Float16* wgm = (_Float16*)(ws + ((TIER == 2) ? G_WGM : (TIER == 1) ? B_WGM : F_WGM));
    _Float16* wuh = (_Float16*)(ws + ((TIER == 2) ? G_WUH : (TIER == 1) ? B_WUH : F_WUH));
    _Float16* wum = (_Float16*)(ws + ((TIER == 2) ? G_WUM : (TIER == 1) ? B_WUM : F_WUM));
    float*    H   = (float*)(ws + OFF_H);
    _Float16* hq  = (TIER == 2) ? (_Float16*)(ws + G_XQH) : (_Float16*)(ws + OFF_HQ);
    _Float16* wdq = (_Float16*)(ws + OFF_WDQ);
    _Float16* xh  = (_Float16*)(ws + OFF_XH);
    _Float16* t1  = (_Float16*)(ws + OFF_T1);
    _Float16* lrAT = (_Float16*)(ws + OFF_LRAT);
    _Float16* lrBT = (_Float16*)(ws + OFF_LRBT);

    init_kernel<<<1, 64, 0, stream>>>(sc);
    absmax4_kernel<<<dim3(1024, 4), 256, 0, stream>>>(x, wg, wu, wd, sc + 0);

    if (TIER == 2) {
        quant_split16_kernel<<<8192, 256, 0, stream>>>(x, 4096, 256, 248,
                                                       upidx, sc + 0, xqh, xqm);
        for (int c = 0; c < 6; ++c) {
            const int frow0 = c * 2048;
            const int nrows = (frow0 + 2048 <= 11008) ? 2048 : (11008 - frow0);
            quant_wgu_kernel<<<2 * nrows, 256, 0, stream>>>(
                wg + (long)frow0 * 4096, wu + (long)frow0 * 4096, nrows,
                upidx, sc + 1, sc + 2, wgh, wgm, wuh, wum);
            gemm1_kernel<<<dim3(64, nrows / 64), 512, 0, stream>>>(
                xqh, xqm, wgh, wgm, wuh, wum, H, 0, frow0, hmax64);
        }
        requant_h_direct_kernel<<<8192, 256, 0, stream>>>(H, hq, dnidx, hmax64);
    } else if (TIER == 1) {
        for (int m = 0; m < 2; ++m) {
            const long xrow0 = (long)m * 4096;
            quant_split16_kernel<<<4096, 256, 0, stream>>>(x + xrow0 * 4096, 4096, 256, 248,
                                                           upidx, sc + 0, xqh, xqm);
            for (int c = 0; c < 6; ++c) {
                const int frow0 = c * 2048;
                const int nrows = (frow0 + 2048 <= 11008) ? 2048 : (11008 - frow0);
                quant_wgu_kernel<<<2 * nrows, 256, 0, stream>>>(
                    wg + (long)frow0 * 4096, wu + (long)frow0 * 4096, nrows,
                    upidx, sc + 1, sc + 2, wgh, wgm, wuh, wum);
                gemm1_kernel<<<dim3(32, nrows / 64), 512, 0, stream>>>(
                    xqh, xqm, wgh, wgm, wuh, wum, H, (int)xrow0, frow0, hmax64);
            }
        }
        requant_h_kernel<<<1, 256, 0, stream>>>(H, 8191, dnidx, hmax64);
        for (int d = 1; d <= 13; ++d) {
            int L = 8192 - (1 << d);
            int n = 1 << (d - 1);
            requant_h_kernel<<<n, 256, 0, stream>>>(H, L, dnidx, hmax64);
        }
    } else {
        for (int m = 0; m < 4; ++m) {
            const long xrow0 = (long)m * 2048;
            quant_split16_kernel<<<2048, 256, 0, stream>>>(x + xrow0 * 4096, 4096, 256, 248,
                                                           upidx, sc + 0, xqh, xqm);
            for (int c = 0; c < 11; ++c) {
                const int frow0 = c * 1024;
                const int nrows = (frow0 + 1024 <= 11008) ? 1024 : (11008 - frow0);
                quant_wgu_kernel<<<2 * nrows, 256, 0, stream>>>(
                    wg + (long)frow0 * 4096, wu + (long)frow0 * 4096, nrows,
                    upidx, sc + 1, sc + 2, wgh, wgm, wuh, wum);
                gemm1_kernel<<<dim3(16, nrows / 64), 512, 0, stream>>>(
                    xqh, xqm, wgh, wgm, wuh, wum, H, (int)xrow0, frow0, hmax64);
            }
        }
        requant_h_kernel<<<1, 256, 0, stream>>>(H, 8191, dnidx, hmax64);
        for (int d = 1; d <= 13; ++d) {
            int L = 8192 - (1 << d);
            int n = 1 << (d - 1);
            requant_h_kernel<<<n, 256, 0, stream>>>(H, L, dnidx, hmax64);
        }
    }

    // late phase (overlays in H's dead region)
    convert_f16_kernel<<<2048, 256, 0, stream>>>(x, 33554432 / 4, xh);
    transpose_f16_kernel<<<(4096 * 64 + 255) / 256, 256, 0, stream>>>(lrA, 4096, 64, lrAT);
    transpose_f16_kernel<<<(64 * 4096 + 255) / 256, 256, 0, stream>>>(lrB, 64, 4096, lrBT);
    lr1_kernel<<<64, 256, 0, stream>>>(xh, lrAT, t1);
    quant_rows_kernel<<<4096, 256, 0, stream>>>(wd, 11008, 688, 680, dnidx, sc + 3, wdq);
    gemm2_kernel<<<dim3(64, 32), 256, 0, stream>>>(hq, wdq, scale, t1, lrBT, out);
}

// Round 18
// 7927.928 us; speedup vs baseline: 1.4538x; 1.4538x over previous
//
#include <hip/hip_runtime.h>
#include <stdint.h>

#define DEVINL __device__ __forceinline__

typedef __attribute__((ext_vector_type(8))) _Float16 half8;
typedef __attribute__((ext_vector_type(4))) _Float16 half4;
typedef __attribute__((ext_vector_type(4))) float f32x4;

typedef __attribute__((address_space(1))) void* gas_ptr;
typedef __attribute__((address_space(3))) void* las_ptr;

DEVINL void g2l16(const void* g, void* l) {
    __builtin_amdgcn_global_load_lds((gas_ptr)g, (las_ptr)l, 16, 0, 0);
}

// ---------------------------------------------------------------- utilities

__global__ void init_kernel(unsigned* u) {
    if (threadIdx.x < 16) u[threadIdx.x] = 0u;
}

__global__ void sentinel_kernel(float* out) { out[0] = 1.0e9f; }

// absmax of x + the 3 weight tensors in one launch; blockIdx.y selects tensor.
__global__ void absmax4_kernel(const float* __restrict__ x,
                               const float* __restrict__ w0,
                               const float* __restrict__ w1,
                               const float* __restrict__ w2,
                               unsigned* __restrict__ out) {
    const float* src; int n4;
    if (blockIdx.y == 0)      { src = x;  n4 = 8388608; }
    else if (blockIdx.y == 1) { src = w0; n4 = 11272192; }
    else if (blockIdx.y == 2) { src = w1; n4 = 11272192; }
    else                      { src = w2; n4 = 11272192; }
    int i = blockIdx.x * blockDim.x + threadIdx.x;
    const int stride = gridDim.x * blockDim.x;
    float m = 0.0f;
    const float4* s4 = (const float4*)src;
    for (; i < n4; i += stride) {
        float4 v = s4[i];
        m = fmaxf(m, fmaxf(fmaxf(fabsf(v.x), fabsf(v.y)),
                           fmaxf(fabsf(v.z), fabsf(v.w))));
    }
    #pragma unroll
    for (int off = 32; off > 0; off >>= 1) m = fmaxf(m, __shfl_down(m, off));
    if ((threadIdx.x & 63) == 0) atomicMax(out + blockIdx.y, __float_as_uint(m));
}

__global__ void convert_f16_kernel(const float* __restrict__ src, int n4,
                                   _Float16* __restrict__ dst) {
    int i = blockIdx.x * blockDim.x + threadIdx.x;
    const int stride = gridDim.x * blockDim.x;
    const float4* s4 = (const float4*)src;
    half4* d4 = (half4*)dst;
    for (; i < n4; i += stride) {
        float4 v = s4[i];
        half4 h;
        h.x = (_Float16)v.x; h.y = (_Float16)v.y;
        h.z = (_Float16)v.z; h.w = (_Float16)v.w;
        d4[i] = h;
    }
}

__global__ void transpose_f16_kernel(const float* __restrict__ src, int rows, int cols,
                                     _Float16* __restrict__ dst) {
    long i = (long)blockIdx.x * blockDim.x + threadIdx.x;
    if (i < (long)rows * cols) {
        int r = (int)(i / cols), c = (int)(i % cols);
        dst[(long)c * rows + r] = (_Float16)src[i];
    }
}

// ---------------------------------------------------------------- quantization (fp64)

DEVINL double lvl64(double aa) {
    if      (aa >= 5.0)  return 6.0;
    else if (aa >= 3.5)  return 4.0;
    else if (aa >= 2.5)  return 3.0;
    else if (aa >= 1.75) return 2.0;
    else if (aa >= 1.25) return 1.5;
    else if (aa >= 0.75) return 1.0;
    else if (aa >= 0.25) return 0.5;
    return 0.0;
}

// per-row gather+quantize -> fp16 hi + fp16 mid (identical math to green rounds)
DEVINL void quant_split_row(const float* __restrict__ srow,
                            _Float16* __restrict__ hrow, _Float16* __restrict__ mrow,
                            int nb, int nq, const int* __restrict__ idx, double s,
                            int tid, int nthr) {
    for (int j = tid; j < nb; j += nthr) {
        const int* ip = idx + (j << 4);
        double v[16];
        #pragma unroll
        for (int i = 0; i < 16; ++i) v[i] = (double)srow[ip[i]];
        if (j < nq) {
            double t[16];
            #pragma unroll
            for (int i = 0; i < 16; ++i) t[i] = v[i] / s;
            double bmax = 0.0;
            #pragma unroll
            for (int i = 0; i < 16; ++i) bmax = fmax(bmax, fabs(t[i]));
            double sb = fmin(fmax(bmax / 6.0, 1e-12), 448.0);
            #pragma unroll
            for (int i = 0; i < 16; ++i) {
                double a = t[i] / sb;
                v[i] = (copysign(lvl64(fabs(a)), a) * sb) * s;
            }
        }
        _Float16 h[16], m[16];
        #pragma unroll
        for (int i = 0; i < 16; ++i) {
            _Float16 hi = (_Float16)(float)v[i];
            double r = v[i] - (double)(float)hi;
            h[i] = hi;
            m[i] = (_Float16)(float)(r * 4096.0);
        }
        *(half8*)(hrow + (j << 4))     = *(half8*)&h[0];
        *(half8*)(hrow + (j << 4) + 8) = *(half8*)&h[8];
        *(half8*)(mrow + (j << 4))     = *(half8*)&m[0];
        *(half8*)(mrow + (j << 4) + 8) = *(half8*)&m[8];
    }
}

__global__ void quant_split16_kernel(const float* __restrict__ src, int D, int nb, int nq,
                                     const int* __restrict__ idx,
                                     const unsigned* __restrict__ smax_bits,
                                     _Float16* __restrict__ dhi,
                                     _Float16* __restrict__ dmid) {
    double s = fmax((double)__uint_as_float(*smax_bits) / 2688.0, 1e-12);
    quant_split_row(src + (long)blockIdx.x * D,
                    dhi + (long)blockIdx.x * D, dmid + (long)blockIdx.x * D,
                    nb, nq, idx, s, threadIdx.x, blockDim.x);
}

// merged wg+wu chunk quantization: grid = 2*nrows; first half wg, second half wu.
__global__ void quant_wgu_kernel(const float* __restrict__ wg, const float* __restrict__ wu,
                                 int nrows, const int* __restrict__ idx,
                                 const unsigned* __restrict__ sg_bits,
                                 const unsigned* __restrict__ su_bits,
                                 _Float16* __restrict__ wgh, _Float16* __restrict__ wgm,
                                 _Float16* __restrict__ wuh, _Float16* __restrict__ wum) {
    const bool isU = (int)blockIdx.x >= nrows;
    const int r = isU ? (blockIdx.x - nrows) : blockIdx.x;
    const float* src = (isU ? wu : wg) + (long)r * 4096;
    _Float16* dh = (isU ? wuh : wgh) + (long)r * 4096;
    _Float16* dm = (isU ? wum : wgm) + (long)r * 4096;
    double s = fmax((double)__uint_as_float(isU ? *su_bits : *sg_bits) / 2688.0, 1e-12);
    quant_split_row(src, dh, dm, 256, 248, idx, s, threadIdx.x, blockDim.x);
}

__global__ void quant_rows_kernel(const float* __restrict__ src, int D, int nb, int nq,
                                  const int* __restrict__ idx,
                                  const unsigned* __restrict__ smax_bits,
                                  _Float16* __restrict__ dst) {
    const float* srow = src + (long)blockIdx.x * D;
    _Float16* drow = dst + (long)blockIdx.x * D;
    double s = fmax((double)__uint_as_float(*smax_bits) / 2688.0, 1e-12);
    for (int j = threadIdx.x; j < nb; j += blockDim.x) {
        const int* ip = idx + (j << 4);
        double v[16];
        #pragma unroll
        for (int i = 0; i < 16; ++i) v[i] = (double)srow[ip[i]];
        _Float16 o[16];
        if (j >= nq) {
            #pragma unroll
            for (int i = 0; i < 16; ++i) o[i] = (_Float16)(float)v[i];
        } else {
            double t[16];
            #pragma unroll
            for (int i = 0; i < 16; ++i) t[i] = v[i] / s;
            double bmax = 0.0;
            #pragma unroll
            for (int i = 0; i < 16; ++i) bmax = fmax(bmax, fabs(t[i]));
            double sb = fmin(fmax(bmax / 6.0, 1e-12), 448.0);
            #pragma unroll
            for (int i = 0; i < 16; ++i) {
                double a = t[i] / sb;
                o[i] = (_Float16)(float)((copysign(lvl64(fabs(a)), a) * sb) * s);
            }
        }
        *(half8*)(drow + (j << 4))     = *(half8*)&o[0];
        *(half8*)(drow + (j << 4) + 8) = *(half8*)&o[8];
    }
}

// tree-variant (tiers 0/1): in-place overlay, ordered by the launcher's tree
__global__ void requant_h_kernel(float* __restrict__ H, int rowbase,
                                 const int* __restrict__ idx,
                                 const unsigned long long* __restrict__ hmax_bits) {
    __shared__ __align__(16) _Float16 buf[11008];
    const int r = rowbase + blockIdx.x;
    const float* srow = H + (long)r * 11008;
    _Float16* drow = (_Float16*)((char*)H + 180355072L) + (long)r * 11008;
    double s = fmax(__longlong_as_double((long long)*hmax_bits) / 2688.0, 1e-12);
    for (int j = threadIdx.x; j < 688; j += blockDim.x) {
        const int* ip = idx + (j << 4);
        double v[16];
        #pragma unroll
        for (int i = 0; i < 16; ++i) v[i] = (double)srow[ip[i]];
        if (j < 680) {
            double t[16];
            #pragma unroll
            for (int i = 0; i < 16; ++i) t[i] = v[i] / s;
            double bmax = 0.0;
            #pragma unroll
            for (int i = 0; i < 16; ++i) bmax = fmax(bmax, fabs(t[i]));
            double sb = fmin(fmax(bmax / 6.0, 1e-12), 448.0);
            #pragma unroll
            for (int i = 0; i < 16; ++i) {
                double a = t[i] / sb;
                v[i] = (copysign(lvl64(fabs(a)), a) * sb) * s;
            }
        }
        #pragma unroll
        for (int i = 0; i < 16; ++i) buf[(j << 4) + i] = (_Float16)(float)v[i];
    }
    __syncthreads();
    uint4* dst4 = (uint4*)drow;
    const uint4* src4 = (const uint4*)buf;
    for (int e = threadIdx.x; e < (11008 * 2) / 16; e += blockDim.x) dst4[e] = src4[e];
}

// direct-variant (tier 2): dst is a disjoint region -> single unordered launch.
__global__ void requant_h_direct_kernel(const float* __restrict__ H,
                                        _Float16* __restrict__ dst,
                                        const int* __restrict__ idx,
                                        const unsigned long long* __restrict__ hmax_bits) {
    const int r = blockIdx.x;
    const float* srow = H + (long)r * 11008;
    _Float16* drow = dst + (long)r * 11008;
    double s = fmax(__longlong_as_double((long long)*hmax_bits) / 2688.0, 1e-12);
    for (int j = threadIdx.x; j < 688; j += blockDim.x) {
        const int* ip = idx + (j << 4);
        double v[16];
        #pragma unroll
        for (int i = 0; i < 16; ++i) v[i] = (double)srow[ip[i]];
        if (j < 680) {
            double t[16];
            #pragma unroll
            for (int i = 0; i < 16; ++i) t[i] = v[i] / s;
            double bmax = 0.0;
            #pragma unroll
            for (int i = 0; i < 16; ++i) bmax = fmax(bmax, fabs(t[i]));
            double sb = fmin(fmax(bmax / 6.0, 1e-12), 448.0);
            #pragma unroll
            for (int i = 0; i < 16; ++i) {
                double a = t[i] / sb;
                v[i] = (copysign(lvl64(fabs(a)), a) * sb) * s;
            }
        }
        _Float16 o[16];
        #pragma unroll
        for (int i = 0; i < 16; ++i) o[i] = (_Float16)(float)v[i];
        *(half8*)(drow + (j << 4))     = *(half8*)&o[0];
        *(half8*)(drow + (j << 4) + 8) = *(half8*)&o[8];
    }
}

// ---------------------------------------------------------------- GEMM 1
// fp16-split GEMM, fp64 chunk-flushed accumulation. Per-element math bit-identical
// to all green rounds (verified in r17: absmax unchanged with this decomposition).
// 128(M)x64(N) tile, 512 thr (8 waves 4x2, wave-tile 32x32), single 64KB LDS
// buffer. launch_bounds(512,2): VGPR cap 256 -> no spill (r17's (512,4) clamped
// VGPR to 64 and spilled fp64 accumulators: WRITE_SIZE 2GB/launch). Expected
// ~112 VGPR -> HW reaches 2 blocks/CU via LDS+VGPR naturally.

__global__ __launch_bounds__(512, 2)
void gemm1_kernel(const _Float16* __restrict__ Ah, const _Float16* __restrict__ Am,
                  const _Float16* __restrict__ Bgh, const _Float16* __restrict__ Bgm,
                  const _Float16* __restrict__ Buh, const _Float16* __restrict__ Bum,
                  float* __restrict__ H, int hrow0, int hcol0,
                  unsigned long long* __restrict__ hmax64) {
    __shared__ __align__(16) _Float16 sAh[8192], sAm[8192];            // 128x64 each
    __shared__ __align__(16) _Float16 sgh[4096], sgm[4096];            // 64x64 each
    __shared__ __align__(16) _Float16 suh[4096], sum_[4096];           // total 64KB
    const int tid = threadIdx.x;
    const int lane = tid & 63, wave = tid >> 6;
    const int wr = wave >> 1, wc = wave & 1;          // 4x2 wave grid
    const int arow0 = blockIdx.x * 128, brow0 = blockIdx.y * 64;

    if ((blockIdx.x ^ blockIdx.y) & 1) __builtin_amdgcn_s_sleep(32);

    const int r0 = tid >> 3, sl = tid & 7;
    const int slx = sl ^ (r0 & 7);
    const _Float16* gAh = Ah  + (long)(arow0 + r0) * 4096 + slx * 8;
    const _Float16* gAm = Am  + (long)(arow0 + r0) * 4096 + slx * 8;
    const _Float16* ggh = Bgh + (long)(brow0 + r0) * 4096 + slx * 8;
    const _Float16* ggm = Bgm + (long)(brow0 + r0) * 4096 + slx * 8;
    const _Float16* guh = Buh + (long)(brow0 + r0) * 4096 + slx * 8;
    const _Float16* gum = Bum + (long)(brow0 + r0) * 4096 + slx * 8;
    const int wo = wave * 512;            // wave-uniform LDS base (elements)
    const long R64 = 64L * 4096;          // +64 rows in source (A pass 2)

#define STAGE1(K0) do { \
        g2l16(gAh + (K0),       sAh + wo); \
        g2l16(gAh + (K0) + R64, sAh + 4096 + wo); \
        g2l16(gAm + (K0),       sAm + wo); \
        g2l16(gAm + (K0) + R64, sAm + 4096 + wo); \
        g2l16(ggh + (K0),       sgh + wo); \
        g2l16(ggm + (K0),       sgm + wo); \
        g2l16(guh + (K0),       suh + wo); \
        g2l16(gum + (K0),       sum_ + wo); \
    } while (0)

    const f32x4 z4 = {0.f, 0.f, 0.f, 0.f};
    f32x4 accg[2][2], accu[2][2], accgX[2][2], accuX[2][2];
    double accgD[2][2][4], accuD[2][2][4];
    #pragma unroll
    for (int i = 0; i < 2; ++i)
        #pragma unroll
        for (int j = 0; j < 2; ++j) {
            accg[i][j] = z4; accu[i][j] = z4; accgX[i][j] = z4; accuX[i][j] = z4;
            #pragma unroll
            for (int r = 0; r < 4; ++r) { accgD[i][j][r] = 0.0; accuD[i][j][r] = 0.0; }
        }

    const int frow = lane & 15;
    const int l4 = lane >> 4;

    for (int t = 0; t < 64; ++t) {
        STAGE1(t << 6);
        __syncthreads();
        __builtin_amdgcn_s_setprio(1);
        #pragma unroll
        for (int kk = 0; kk < 2; ++kk) {
            const int ksl = (kk << 2) + l4;
            half8 ah[2], am2[2], bh[2], bm[2], ch[2], cm[2];
            #pragma unroll
            for (int i = 0; i < 2; ++i) {
                const int ra = wr * 32 + i * 16 + frow;    // 0..127
                const int so = (ksl ^ (ra & 7)) * 8;
                ah[i]  = *(const half8*)(sAh + ra * 64 + so);
                am2[i] = *(const half8*)(sAm + ra * 64 + so);
            }
            #pragma unroll
            for (int j = 0; j < 2; ++j) {
                const int rb = wc * 32 + j * 16 + frow;    // 0..63
                const int so = (ksl ^ (rb & 7)) * 8;
                bh[j] = *(const half8*)(sgh + rb * 64 + so);
                bm[j] = *(const half8*)(sgm + rb * 64 + so);
                ch[j] = *(const half8*)(suh + rb * 64 + so);
                cm[j] = *(const half8*)(sum_ + rb * 64 + so);
            }
            #pragma unroll
            for (int i = 0; i < 2; ++i)
                #pragma unroll
                for (int j = 0; j < 2; ++j) {
                    accg[i][j]  = __builtin_amdgcn_mfma_f32_16x16x32_f16(ah[i],  bh[j], accg[i][j], 0, 0, 0);
                    accgX[i][j] = __builtin_amdgcn_mfma_f32_16x16x32_f16(ah[i],  bm[j], accgX[i][j], 0, 0, 0);
                    accgX[i][j] = __builtin_amdgcn_mfma_f32_16x16x32_f16(am2[i], bh[j], accgX[i][j], 0, 0, 0);
                    accu[i][j]  = __builtin_amdgcn_mfma_f32_16x16x32_f16(ah[i],  ch[j], accu[i][j], 0, 0, 0);
                    accuX[i][j] = __builtin_amdgcn_mfma_f32_16x16x32_f16(ah[i],  cm[j], accuX[i][j], 0, 0, 0);
                    accuX[i][j] = __builtin_amdgcn_mfma_f32_16x16x32_f16(am2[i], ch[j], accuX[i][j], 0, 0, 0);
                }
        }
        __builtin_amdgcn_s_setprio(0);
        if ((t & 7) == 7) {   // flush every K=512 (cadence identical to green rounds)
            #pragma unroll
            for (int i = 0; i < 2; ++i)
                #pragma unroll
                for (int j = 0; j < 2; ++j) {
                    #pragma unroll
                    for (int r = 0; r < 4; ++r) {
                        accgD[i][j][r] += (double)accg[i][j][r];
                        accuD[i][j][r] += (double)accu[i][j][r];
                    }
                    accg[i][j] = z4; accu[i][j] = z4;
                }
        }
        __syncthreads();
    }
#undef STAGE1

    double lmax = 0.0;
    const int crow = l4 * 4, ccol = lane & 15;
    #pragma unroll
    for (int i = 0; i < 2; ++i) {
        #pragma unroll
        for (int j = 0; j < 2; ++j) {
            const int row = hrow0 + arow0 + wr * 32 + i * 16 + crow;
            const int col = hcol0 + brow0 + wc * 32 + j * 16 + ccol;
            #pragma unroll
            for (int r = 0; r < 4; ++r) {
                double g = accgD[i][j][r] + (double)accgX[i][j][r] * 0x1p-12;
                double u = accuD[i][j][r] + (double)accuX[i][j][r] * 0x1p-12;
                double sig = 1.0 / (1.0 + exp(-g));
                double h = (g * sig) * u;
                lmax = fmax(lmax, fabs(h));
                H[(long)(row + r) * 11008 + col] = (float)h;
            }
        }
    }
    #pragma unroll
    for (int off = 32; off > 0; off >>= 1) lmax = fmax(lmax, __shfl_down(lmax, off));
    if (lane == 0) atomicMax(hmax64, (unsigned long long)__double_as_longlong(lmax));
}

// ---------------------------------------------------------------- GEMM 2
// fp16, 128x128 tile, BK=128, 16-slot row swizzle (proven ~790us, at its
// staging-volume roofline); out = (Hq @ Wd^T)*scale + T1 @ lrB

__global__ __launch_bounds__(256, 2)
void gemm2_kernel(const _Float16* __restrict__ A,    // hq  [8192][11008]
                  const _Float16* __restrict__ B,    // wdq [4096][11008]
                  const float* __restrict__ scale,   // [4096]
                  const _Float16* __restrict__ T1,   // [8192][64]
                  const _Float16* __restrict__ BT,   // lrBT [4096][64]
                  float* __restrict__ out) {
    __shared__ __align__(16) _Float16 sA[128 * 128];   // 32 KB
    __shared__ __align__(16) _Float16 sB[128 * 128];   // 32 KB
    const int tid = threadIdx.x;
    const int lane = tid & 63, wave = tid >> 6;
    const int wr = wave >> 1, wc = wave & 1;
    const int arow0 = blockIdx.x * 128, brow0 = blockIdx.y * 128;

    const int qrow = tid >> 4, qsl = tid & 15;
    const int qslx = qsl ^ (qrow & 15);
    const _Float16* gA = A + (long)(arow0 + qrow) * 11008 + qslx * 8;
    const _Float16* gB = B + (long)(brow0 + qrow) * 11008 + qslx * 8;
    const long QROW16 = 16L * 11008;

    const f32x4 z4 = {0.f, 0.f, 0.f, 0.f};
    f32x4 acc[4][4];
    #pragma unroll
    for (int i = 0; i < 4; ++i)
        #pragma unroll
        for (int j = 0; j < 4; ++j) acc[i][j] = z4;

    const int frow = lane & 15;
    const int l4 = lane >> 4;

    for (int k0 = 0; k0 < 11008; k0 += 128) {
        #pragma unroll
        for (int q = 0; q < 8; ++q) {
            g2l16(gA + k0 + q * QROW16, sA + q * 2048 + wave * 512);
            g2l16(gB + k0 + q * QROW16, sB + q * 2048 + wave * 512);
        }
        __syncthreads();
        #pragma unroll
        for (int kk = 0; kk < 4; ++kk) {
            const int ksl = (kk << 2) + l4;
            half8 af[4], bf[4];
            #pragma unroll
            for (int i = 0; i < 4; ++i) {
                const int ra = wr * 64 + i * 16 + frow;
                af[i] = *(const half8*)(sA + ra * 128 + ((ksl ^ (ra & 15)) * 8));
            }
            #pragma unroll
            for (int j = 0; j < 4; ++j) {
                const int rb = wc * 64 + j * 16 + frow;
                bf[j] = *(const half8*)(sB + rb * 128 + ((ksl ^ (rb & 15)) * 8));
            }
            #pragma unroll
            for (int i = 0; i < 4; ++i)
                #pragma unroll
                for (int j = 0; j < 4; ++j)
                    acc[i][j] = __builtin_amdgcn_mfma_f32_16x16x32_f16(af[i], bf[j], acc[i][j], 0, 0, 0);
        }
        __syncthreads();
    }

    // rank-64 low-rank tail (separate accumulator; scale must not apply to it)
    f32x4 accL[4][4];
    #pragma unroll
    for (int i = 0; i < 4; ++i)
        #pragma unroll
        for (int j = 0; j < 4; ++j) accL[i][j] = z4;
    const int r8 = tid >> 3, sl8 = tid & 7;
    const int slx8 = sl8 ^ (r8 & 7);
    const _Float16* gT = T1 + (long)(arow0 + r8) * 64 + slx8 * 8;
    const _Float16* gL = BT + (long)(brow0 + r8) * 64 + slx8 * 8;
    #pragma unroll
    for (int q = 0; q < 4; ++q) {
        g2l16(gT + q * (32L * 64), sA + q * 2048 + wave * 512);
        g2l16(gL + q * (32L * 64), sB + q * 2048 + wave * 512);
    }
    __syncthreads();
    #pragma unroll
    for (int kk = 0; kk < 2; ++kk) {
        const int ksl = (kk << 2) + l4;
        half8 af[4], bf[4];
        #pragma unroll
        for (int i = 0; i < 4; ++i) {
            const int ra = wr * 64 + i * 16 + frow;
            af[i] = *(const half8*)(sA + ra * 64 + (ksl ^ (ra & 7)) * 8);
        }
        #pragma unroll
        for (int j = 0; j < 4; ++j) {
            const int rb = wc * 64 + j * 16 + frow;
            bf[j] = *(const half8*)(sB + rb * 64 + (ksl ^ (rb & 7)) * 8);
        }
        #pragma unroll
        for (int i = 0; i < 4; ++i)
            #pragma unroll
            for (int j = 0; j < 4; ++j)
                accL[i][j] = __builtin_amdgcn_mfma_f32_16x16x32_f16(af[i], bf[j], accL[i][j], 0, 0, 0);
    }

    const int crow = l4 * 4, ccol = lane & 15;
    #pragma unroll
    for (int j = 0; j < 4; ++j) {
        const int col = brow0 + wc * 64 + j * 16 + ccol;
        const float sc = scale[col];
        #pragma unroll
        for (int i = 0; i < 4; ++i) {
            const int row = arow0 + wr * 64 + i * 16 + crow;
            #pragma unroll
            for (int r = 0; r < 4; ++r)
                out[(long)(row + r) * 4096 + col] = acc[i][j][r] * sc + accL[i][j][r];
        }
    }
}

// T1 = xh @ lrA  (M=8192, N=64, K=4096), fp16. (tiny; unchanged)
__global__ __launch_bounds__(256, 2)
void lr1_kernel(const _Float16* __restrict__ X,
                const _Float16* __restrict__ AT,
                _Float16* __restrict__ T1) {
    __shared__ __align__(16) _Float16 sA[128 * 32];
    __shared__ __align__(16) _Float16 sB[64 * 32];
    const int tid = threadIdx.x;
    const int lane = tid & 63, wave = tid >> 6;
    const int arow0 = blockIdx.x * 128;

    const int rs = tid >> 2, cs8 = (tid & 3) * 8;
    const _Float16* gA = X + (long)(arow0 + rs) * 4096 + cs8;
    const _Float16* gB = AT + (long)rs * 4096 + cs8;
    _Float16* lA = sA + wave * 512;
    _Float16* lB = sB + wave * 512;

    const f32x4 z4 = {0.f, 0.f, 0.f, 0.f};
    f32x4 acc[2][4];
    #pragma unroll
    for (int i = 0; i < 2; ++i)
        #pragma unroll
        for (int j = 0; j < 4; ++j) acc[i][j] = z4;

    const int frow = lane & 15;
    const int fke = (lane >> 4) * 8;

    for (int k0 = 0; k0 < 4096; k0 += 32) {
        g2l16(gA + k0,             lA);
        g2l16(gA + k0 + 64 * 4096, lA + 2048);
        g2l16(gB + k0, lB);
        __syncthreads();
        half8 af[2], bf[4];
        #pragma unroll
        for (int i = 0; i < 2; ++i)
            af[i] = *(const half8*)(sA + (wave * 32 + i * 16 + frow) * 32 + fke);
        #pragma unroll
        for (int j = 0; j < 4; ++j)
            bf[j] = *(const half8*)(sB + (j * 16 + frow) * 32 + fke);
        #pragma unroll
        for (int i = 0; i < 2; ++i)
            #pragma unroll
            for (int j = 0; j < 4; ++j)
                acc[i][j] = __builtin_amdgcn_mfma_f32_16x16x32_f16(af[i], bf[j], acc[i][j], 0, 0, 0);
        __syncthreads();
    }

    const int crow = (lane >> 4) * 4, ccol = lane & 15;
    #pragma unroll
    for (int i = 0; i < 2; ++i)
        #pragma unroll
        for (int j = 0; j < 4; ++j) {
            const int row = arow0 + wave * 32 + i * 16 + crow;
            const int col = j * 16 + ccol;
            #pragma unroll
            for (int r = 0; r < 4; ++r)
                T1[(long)(row + r) * 64 + col] = (_Float16)acc[i][j][r];
        }
}

// ---------------------------------------------------------------- launch

extern "C" void kernel_launch(void* const* d_in, const int* in_sizes, int n_in,
                              void* d_out, int out_size, void* d_ws, size_t ws_size,
                              hipStream_t stream) {
    const float* x     = (const float*)d_in[0];
    const float* wg    = (const float*)d_in[1];
    const float* wu    = (const float*)d_in[2];
    const float* wd    = (const float*)d_in[3];
    const float* scale = (const float*)d_in[4];
    const float* lrA   = (const float*)d_in[5];
    const float* lrB   = (const float*)d_in[6];
    const int* upidx   = (const int*)d_in[7];
    const int* dnidx   = (const int*)d_in[8];
    float* out = (float*)d_out;
    char* ws = (char*)d_ws;

    // FALLBACK (proven r13): m-chunks 2048, f-chunks 1024. 427,819,264 B.
    const long F_XQH = 256;
    const long F_XQM = F_XQH + 16777216L;
    const long F_WGH = F_XQM + 16777216L;
    const long F_WGM = F_WGH + 8388608L;
    const long F_WUH = F_WGM + 8388608L;
    const long F_WUM = F_WUH + 8388608L;
    const long F_H   = F_WUM + 8388608L;
    const long NEED_FB = F_H + 360710144L;

    // BIG (proven r14): m-chunks 4096, f-chunks 2048. 494,928,128 B.
    const long B_XQH = 256;
    const long B_XQM = B_XQH + 33554432L;
    const long B_WGH = B_XQM + 33554432L;
    const long B_WGM = B_WGH + 16777216L;
    const long B_WUH = B_WGM + 16777216L;
    const long B_WUM = B_WUH + 16777216L;
    const long B_H   = B_WUM + 16777216L;
    const long NEED_BIG = B_H + 360710144L;

    // HUGE (proven r15/16): full 8192-row xq, f-chunks 2048. 562,036,992 B.
    const long G_XQH = 256;
    const long G_XQM = G_XQH + 67108864L;
    const long G_WGH = G_XQM + 67108864L;
    const long G_WGM = G_WGH + 16777216L;
    const long G_WUH = G_WGM + 16777216L;
    const long G_WUM = G_WUH + 16777216L;
    const long G_H   = G_WUM + 16777216L;
    const long NEED_HUGE = G_H + 360710144L;

    if (ws_size < (size_t)NEED_FB) { sentinel_kernel<<<1, 1, 0, stream>>>(out); return; }
    const int TIER = (ws_size >= (size_t)NEED_HUGE) ? 2
                   : (ws_size >= (size_t)NEED_BIG) ? 1 : 0;

    const long OFF_H = (TIER == 2) ? G_H : (TIER == 1) ? B_H : F_H;
    const long OFF_HQ   = OFF_H + 180355072L;
    const long OFF_WDQ  = OFF_H;
    const long OFF_XH   = OFF_H + 90177536L;
    const long OFF_T1   = OFF_XH + 67108864L;
    const long OFF_LRAT = OFF_T1 + 1048576L;
    const long OFF_LRBT = OFF_LRAT + 524288L;

    unsigned* sc = (unsigned*)ws;
    unsigned long long* hmax64 = (unsigned long long*)(ws + 32);
    _Float16* xqh = (_Float16*)(ws + ((TIER == 2) ? G_XQH : (TIER == 1) ? B_XQH : F_XQH));
    _Float16* xqm = (_Float16*)(ws + ((TIER == 2) ? G_XQM : (TIER == 1) ? B_XQM : F_XQM));
    _Float16* wgh = (_Float16*)(ws + ((TIER == 2) ? G_WGH : (TIER == 1) ? B_WGH : F_WGH));
    _Float16* wgm = (_Float16*)(ws + ((TIER == 2) ? G_WGM : (TIER == 1) ? B_WGM : F_WGM));
    _Float16* wuh = (_Float16*)(ws + ((TIER == 2) ? G_WUH : (TIER == 1) ? B_WUH : F_WUH));
    _Float16* wum = (_Float16*)(ws + ((TIER == 2) ? G_WUM : (TIER == 1) ? B_WUM : F_WUM));
    float*    H   = (float*)(ws + OFF_H);
    _Float16* hq  = (TIER == 2) ? (_Float16*)(ws + G_XQH) : (_Float16*)(ws + OFF_HQ);
    _Float16* wdq = (_Float16*)(ws + OFF_WDQ);
    _Float16* xh  = (_Float16*)(ws + OFF_XH);
    _Float16* t1  = (_Float16*)(ws + OFF_T1);
    _Float16* lrAT = (_Float16*)(ws + OFF_LRAT);
    _Float16* lrBT = (_Float16*)(ws + OFF_LRBT);

    init_kernel<<<1, 64, 0, stream>>>(sc);
    absmax4_kernel<<<dim3(1024, 4), 256, 0, stream>>>(x, wg, wu, wd, sc + 0);

    if (TIER == 2) {
        quant_split16_kernel<<<8192, 256, 0, stream>>>(x, 4096, 256, 248,
                                                       upidx, sc + 0, xqh, xqm);
        for (int c = 0; c < 6; ++c) {
            const int frow0 = c * 2048;
            const int nrows = (frow0 + 2048 <= 11008) ? 2048 : (11008 - frow0);
            quant_wgu_kernel<<<2 * nrows, 256, 0, stream>>>(
                wg + (long)frow0 * 4096, wu + (long)frow0 * 4096, nrows,
                upidx, sc + 1, sc + 2, wgh, wgm, wuh, wum);
            gemm1_kernel<<<dim3(64, nrows / 64), 512, 0, stream>>>(
                xqh, xqm, wgh, wgm, wuh, wum, H, 0, frow0, hmax64);
        }
        requant_h_direct_kernel<<<8192, 256, 0, stream>>>(H, hq, dnidx, hmax64);
    } else if (TIER == 1) {
        for (int m = 0; m < 2; ++m) {
            const long xrow0 = (long)m * 4096;
            quant_split16_kernel<<<4096, 256, 0, stream>>>(x + xrow0 * 4096, 4096, 256, 248,
                                                           upidx, sc + 0, xqh, xqm);
            for (int c = 0; c < 6; ++c) {
                const int frow0 = c * 2048;
                const int nrows = (frow0 + 2048 <= 11008) ? 2048 : (11008 - frow0);
                quant_wgu_kernel<<<2 * nrows, 256, 0, stream>>>(
                    wg + (long)frow0 * 4096, wu + (long)frow0 * 4096, nrows,
                    upidx, sc + 1, sc + 2, wgh, wgm, wuh, wum);
                gemm1_kernel<<<dim3(32, nrows / 64), 512, 0, stream>>>(
                    xqh, xqm, wgh, wgm, wuh, wum, H, (int)xrow0, frow0, hmax64);
            }
        }
        requant_h_kernel<<<1, 256, 0, stream>>>(H, 8191, dnidx, hmax64);
        for (int d = 1; d <= 13; ++d) {
            int L = 8192 - (1 << d);
            int n = 1 << (d - 1);
            requant_h_kernel<<<n, 256, 0, stream>>>(H, L, dnidx, hmax64);
        }
    } else {
        for (int m = 0; m < 4; ++m) {
            const long xrow0 = (long)m * 2048;
            quant_split16_kernel<<<2048, 256, 0, stream>>>(x + xrow0 * 4096, 4096, 256, 248,
                                                           upidx, sc + 0, xqh, xqm);
            for (int c = 0; c < 11; ++c) {
                const int frow0 = c * 1024;
                const int nrows = (frow0 + 1024 <= 11008) ? 1024 : (11008 - frow0);
                quant_wgu_kernel<<<2 * nrows, 256, 0, stream>>>(
                    wg + (long)frow0 * 4096, wu + (long)frow0 * 4096, nrows,
                    upidx, sc + 1, sc + 2, wgh, wgm, wuh, wum);
                gemm1_kernel<<<dim3(16, nrows / 64), 512, 0, stream>>>(
                    xqh, xqm, wgh, wgm, wuh, wum, H, (int)xrow0, frow0, hmax64);
            }
        }
        requant_h_kernel<<<1, 256, 0, stream>>>(H, 8191, dnidx, hmax64);
        for (int d = 1; d <= 13; ++d) {
            int L = 8192 - (1 << d);
            int n = 1 << (d - 1);
            requant_h_kernel<<<n, 256, 0, stream>>>(H, L, dnidx, hmax64);
        }
    }

    // late phase (overlays in H's dead region)
    convert_f16_kernel<<<2048, 256, 0, stream>>>(x, 33554432 / 4, xh);
    transpose_f16_kernel<<<(4096 * 64 + 255) / 256, 256, 0, stream>>>(lrA, 4096, 64, lrAT);
    transpose_f16_kernel<<<(64 * 4096 + 255) / 256, 256, 0, stream>>>(lrB, 64, 4096, lrBT);
    lr1_kernel<<<64, 256, 0, stream>>>(xh, lrAT, t1);
    quant_rows_kernel<<<4096, 256, 0, stream>>>(wd, 11008, 688, 680, dnidx, sc + 3, wdq);
    gemm2_kernel<<<dim3(64, 32), 256, 0, stream>>>(hq, wdq, scale, t1, lrBT, out);
}

// Round 19
// 6770.326 us; speedup vs baseline: 1.7024x; 1.1710x over previous
//
#include <hip/hip_runtime.h>
#include <stdint.h>

#define DEVINL __device__ __forceinline__

typedef __attribute__((ext_vector_type(8))) _Float16 half8;
typedef __attribute__((ext_vector_type(4))) _Float16 half4;
typedef __attribute__((ext_vector_type(4))) float f32x4;

typedef __attribute__((address_space(1))) void* gas_ptr;
typedef __attribute__((address_space(3))) void* las_ptr;

DEVINL void g2l16(const void* g, void* l) {
    __builtin_amdgcn_global_load_lds((gas_ptr)g, (las_ptr)l, 16, 0, 0);
}

// ---------------------------------------------------------------- utilities

__global__ void init_kernel(unsigned* u) {
    if (threadIdx.x < 16) u[threadIdx.x] = 0u;
}

__global__ void sentinel_kernel(float* out) { out[0] = 1.0e9f; }

// absmax of x + the 3 weight tensors in one launch; blockIdx.y selects tensor.
__global__ void absmax4_kernel(const float* __restrict__ x,
                               const float* __restrict__ w0,
                               const float* __restrict__ w1,
                               const float* __restrict__ w2,
                               unsigned* __restrict__ out) {
    const float* src; int n4;
    if (blockIdx.y == 0)      { src = x;  n4 = 8388608; }
    else if (blockIdx.y == 1) { src = w0; n4 = 11272192; }
    else if (blockIdx.y == 2) { src = w1; n4 = 11272192; }
    else                      { src = w2; n4 = 11272192; }
    int i = blockIdx.x * blockDim.x + threadIdx.x;
    const int stride = gridDim.x * blockDim.x;
    float m = 0.0f;
    const float4* s4 = (const float4*)src;
    for (; i < n4; i += stride) {
        float4 v = s4[i];
        m = fmaxf(m, fmaxf(fmaxf(fabsf(v.x), fabsf(v.y)),
                           fmaxf(fabsf(v.z), fabsf(v.w))));
    }
    #pragma unroll
    for (int off = 32; off > 0; off >>= 1) m = fmaxf(m, __shfl_down(m, off));
    if ((threadIdx.x & 63) == 0) atomicMax(out + blockIdx.y, __float_as_uint(m));
}

__global__ void convert_f16_kernel(const float* __restrict__ src, int n4,
                                   _Float16* __restrict__ dst) {
    int i = blockIdx.x * blockDim.x + threadIdx.x;
    const int stride = gridDim.x * blockDim.x;
    const float4* s4 = (const float4*)src;
    half4* d4 = (half4*)dst;
    for (; i < n4; i += stride) {
        float4 v = s4[i];
        half4 h;
        h.x = (_Float16)v.x; h.y = (_Float16)v.y;
        h.z = (_Float16)v.z; h.w = (_Float16)v.w;
        d4[i] = h;
    }
}

__global__ void transpose_f16_kernel(const float* __restrict__ src, int rows, int cols,
                                     _Float16* __restrict__ dst) {
    long i = (long)blockIdx.x * blockDim.x + threadIdx.x;
    if (i < (long)rows * cols) {
        int r = (int)(i / cols), c = (int)(i % cols);
        dst[(long)c * rows + r] = (_Float16)src[i];
    }
}

// ---------------------------------------------------------------- quantization (fp64)

DEVINL double lvl64(double aa) {
    if      (aa >= 5.0)  return 6.0;
    else if (aa >= 3.5)  return 4.0;
    else if (aa >= 2.5)  return 3.0;
    else if (aa >= 1.75) return 2.0;
    else if (aa >= 1.25) return 1.5;
    else if (aa >= 0.75) return 1.0;
    else if (aa >= 0.25) return 0.5;
    return 0.0;
}

// per-row gather+quantize -> fp16 hi + fp16 mid (identical math to green rounds)
DEVINL void quant_split_row(const float* __restrict__ srow,
                            _Float16* __restrict__ hrow, _Float16* __restrict__ mrow,
                            int nb, int nq, const int* __restrict__ idx, double s,
                            int tid, int nthr) {
    for (int j = tid; j < nb; j += nthr) {
        const int* ip = idx + (j << 4);
        double v[16];
        #pragma unroll
        for (int i = 0; i < 16; ++i) v[i] = (double)srow[ip[i]];
        if (j < nq) {
            double t[16];
            #pragma unroll
            for (int i = 0; i < 16; ++i) t[i] = v[i] / s;
            double bmax = 0.0;
            #pragma unroll
            for (int i = 0; i < 16; ++i) bmax = fmax(bmax, fabs(t[i]));
            double sb = fmin(fmax(bmax / 6.0, 1e-12), 448.0);
            #pragma unroll
            for (int i = 0; i < 16; ++i) {
                double a = t[i] / sb;
                v[i] = (copysign(lvl64(fabs(a)), a) * sb) * s;
            }
        }
        _Float16 h[16], m[16];
        #pragma unroll
        for (int i = 0; i < 16; ++i) {
            _Float16 hi = (_Float16)(float)v[i];
            double r = v[i] - (double)(float)hi;
            h[i] = hi;
            m[i] = (_Float16)(float)(r * 4096.0);
        }
        *(half8*)(hrow + (j << 4))     = *(half8*)&h[0];
        *(half8*)(hrow + (j << 4) + 8) = *(half8*)&h[8];
        *(half8*)(mrow + (j << 4))     = *(half8*)&m[0];
        *(half8*)(mrow + (j << 4) + 8) = *(half8*)&m[8];
    }
}

__global__ void quant_split16_kernel(const float* __restrict__ src, int D, int nb, int nq,
                                     const int* __restrict__ idx,
                                     const unsigned* __restrict__ smax_bits,
                                     _Float16* __restrict__ dhi,
                                     _Float16* __restrict__ dmid) {
    double s = fmax((double)__uint_as_float(*smax_bits) / 2688.0, 1e-12);
    quant_split_row(src + (long)blockIdx.x * D,
                    dhi + (long)blockIdx.x * D, dmid + (long)blockIdx.x * D,
                    nb, nq, idx, s, threadIdx.x, blockDim.x);
}

// merged wg+wu chunk quantization: grid = 2*nrows; first half wg, second half wu.
__global__ void quant_wgu_kernel(const float* __restrict__ wg, const float* __restrict__ wu,
                                 int nrows, const int* __restrict__ idx,
                                 const unsigned* __restrict__ sg_bits,
                                 const unsigned* __restrict__ su_bits,
                                 _Float16* __restrict__ wgh, _Float16* __restrict__ wgm,
                                 _Float16* __restrict__ wuh, _Float16* __restrict__ wum) {
    const bool isU = (int)blockIdx.x >= nrows;
    const int r = isU ? (blockIdx.x - nrows) : blockIdx.x;
    const float* src = (isU ? wu : wg) + (long)r * 4096;
    _Float16* dh = (isU ? wuh : wgh) + (long)r * 4096;
    _Float16* dm = (isU ? wum : wgm) + (long)r * 4096;
    double s = fmax((double)__uint_as_float(isU ? *su_bits : *sg_bits) / 2688.0, 1e-12);
    quant_split_row(src, dh, dm, 256, 248, idx, s, threadIdx.x, blockDim.x);
}

__global__ void quant_rows_kernel(const float* __restrict__ src, int D, int nb, int nq,
                                  const int* __restrict__ idx,
                                  const unsigned* __restrict__ smax_bits,
                                  _Float16* __restrict__ dst) {
    const float* srow = src + (long)blockIdx.x * D;
    _Float16* drow = dst + (long)blockIdx.x * D;
    double s = fmax((double)__uint_as_float(*smax_bits) / 2688.0, 1e-12);
    for (int j = threadIdx.x; j < nb; j += blockDim.x) {
        const int* ip = idx + (j << 4);
        double v[16];
        #pragma unroll
        for (int i = 0; i < 16; ++i) v[i] = (double)srow[ip[i]];
        _Float16 o[16];
        if (j >= nq) {
            #pragma unroll
            for (int i = 0; i < 16; ++i) o[i] = (_Float16)(float)v[i];
        } else {
            double t[16];
            #pragma unroll
            for (int i = 0; i < 16; ++i) t[i] = v[i] / s;
            double bmax = 0.0;
            #pragma unroll
            for (int i = 0; i < 16; ++i) bmax = fmax(bmax, fabs(t[i]));
            double sb = fmin(fmax(bmax / 6.0, 1e-12), 448.0);
            #pragma unroll
            for (int i = 0; i < 16; ++i) {
                double a = t[i] / sb;
                o[i] = (_Float16)(float)((copysign(lvl64(fabs(a)), a) * sb) * s);
            }
        }
        *(half8*)(drow + (j << 4))     = *(half8*)&o[0];
        *(half8*)(drow + (j << 4) + 8) = *(half8*)&o[8];
    }
}

// tree-variant (tiers 0/1): in-place overlay, ordered by the launcher's tree
__global__ void requant_h_kernel(float* __restrict__ H, int rowbase,
                                 const int* __restrict__ idx,
                                 const unsigned long long* __restrict__ hmax_bits) {
    __shared__ __align__(16) _Float16 buf[11008];
    const int r = rowbase + blockIdx.x;
    const float* srow = H + (long)r * 11008;
    _Float16* drow = (_Float16*)((char*)H + 180355072L) + (long)r * 11008;
    double s = fmax(__longlong_as_double((long long)*hmax_bits) / 2688.0, 1e-12);
    for (int j = threadIdx.x; j < 688; j += blockDim.x) {
        const int* ip = idx + (j << 4);
        double v[16];
        #pragma unroll
        for (int i = 0; i < 16; ++i) v[i] = (double)srow[ip[i]];
        if (j < 680) {
            double t[16];
            #pragma unroll
            for (int i = 0; i < 16; ++i) t[i] = v[i] / s;
            double bmax = 0.0;
            #pragma unroll
            for (int i = 0; i < 16; ++i) bmax = fmax(bmax, fabs(t[i]));
            double sb = fmin(fmax(bmax / 6.0, 1e-12), 448.0);
            #pragma unroll
            for (int i = 0; i < 16; ++i) {
                double a = t[i] / sb;
                v[i] = (copysign(lvl64(fabs(a)), a) * sb) * s;
            }
        }
        #pragma unroll
        for (int i = 0; i < 16; ++i) buf[(j << 4) + i] = (_Float16)(float)v[i];
    }
    __syncthreads();
    uint4* dst4 = (uint4*)drow;
    const uint4* src4 = (const uint4*)buf;
    for (int e = threadIdx.x; e < (11008 * 2) / 16; e += blockDim.x) dst4[e] = src4[e];
}

// direct-variant (tier 2): dst is a disjoint region -> single unordered launch.
__global__ void requant_h_direct_kernel(const float* __restrict__ H,
                                        _Float16* __restrict__ dst,
                                        const int* __restrict__ idx,
                                        const unsigned long long* __restrict__ hmax_bits) {
    const int r = blockIdx.x;
    const float* srow = H + (long)r * 11008;
    _Float16* drow = dst + (long)r * 11008;
    double s = fmax(__longlong_as_double((long long)*hmax_bits) / 2688.0, 1e-12);
    for (int j = threadIdx.x; j < 688; j += blockDim.x) {
        const int* ip = idx + (j << 4);
        double v[16];
        #pragma unroll
        for (int i = 0; i < 16; ++i) v[i] = (double)srow[ip[i]];
        if (j < 680) {
            double t[16];
            #pragma unroll
            for (int i = 0; i < 16; ++i) t[i] = v[i] / s;
            double bmax = 0.0;
            #pragma unroll
            for (int i = 0; i < 16; ++i) bmax = fmax(bmax, fabs(t[i]));
            double sb = fmin(fmax(bmax / 6.0, 1e-12), 448.0);
            #pragma unroll
            for (int i = 0; i < 16; ++i) {
                double a = t[i] / sb;
                v[i] = (copysign(lvl64(fabs(a)), a) * sb) * s;
            }
        }
        _Float16 o[16];
        #pragma unroll
        for (int i = 0; i < 16; ++i) o[i] = (_Float16)(float)v[i];
        *(half8*)(drow + (j << 4))     = *(half8*)&o[0];
        *(half8*)(drow + (j << 4) + 8) = *(half8*)&o[8];
    }
}

// ---------------------------------------------------------------- GEMM 1
// Round-16 proven optimum (6786us total): fp16-split, fp64 chunk-flushed
// accumulation, 64x64 tile, 256 thr (4 waves 2x2), single 48KB LDS buffer,
// plain stage->sync->compute->sync loop, 2 blocks/CU. r17/r18's 128x64/512thr
// variants regressed (spill at (512,4); single-residency at (512,2)).

__global__ __launch_bounds__(256, 2)
void gemm1_kernel(const _Float16* __restrict__ Ah, const _Float16* __restrict__ Am,
                  const _Float16* __restrict__ Bgh, const _Float16* __restrict__ Bgm,
                  const _Float16* __restrict__ Buh, const _Float16* __restrict__ Bum,
                  float* __restrict__ H, int hrow0, int hcol0,
                  unsigned long long* __restrict__ hmax64) {
    __shared__ __align__(16) _Float16 sAh[4096], sAm[4096];            // 64x64 each
    __shared__ __align__(16) _Float16 sgh[4096], sgm[4096];
    __shared__ __align__(16) _Float16 suh[4096], sum_[4096];           // total 48KB
    const int tid = threadIdx.x;
    const int lane = tid & 63, wave = tid >> 6;
    const int wr = wave >> 1, wc = wave & 1;
    const int arow0 = blockIdx.x * 64, brow0 = blockIdx.y * 64;

    if ((blockIdx.x ^ blockIdx.y) & 1) __builtin_amdgcn_s_sleep(32);

    const int r0 = tid >> 3, sl = tid & 7;
    const int slx = sl ^ (r0 & 7);
    const _Float16* gAh = Ah  + (long)(arow0 + r0) * 4096 + slx * 8;
    const _Float16* gAm = Am  + (long)(arow0 + r0) * 4096 + slx * 8;
    const _Float16* ggh = Bgh + (long)(brow0 + r0) * 4096 + slx * 8;
    const _Float16* ggm = Bgm + (long)(brow0 + r0) * 4096 + slx * 8;
    const _Float16* guh = Buh + (long)(brow0 + r0) * 4096 + slx * 8;
    const _Float16* gum = Bum + (long)(brow0 + r0) * 4096 + slx * 8;
    const int wo = wave * 512;
    const long R32 = 32L * 4096;

#define STAGE1(K0) do { \
        g2l16(gAh + (K0),       sAh + wo); \
        g2l16(gAh + (K0) + R32, sAh + wo + 2048); \
        g2l16(gAm + (K0),       sAm + wo); \
        g2l16(gAm + (K0) + R32, sAm + wo + 2048); \
        g2l16(ggh + (K0),       sgh + wo); \
        g2l16(ggh + (K0) + R32, sgh + wo + 2048); \
        g2l16(ggm + (K0),       sgm + wo); \
        g2l16(ggm + (K0) + R32, sgm + wo + 2048); \
        g2l16(guh + (K0),       suh + wo); \
        g2l16(guh + (K0) + R32, suh + wo + 2048); \
        g2l16(gum + (K0),       sum_ + wo); \
        g2l16(gum + (K0) + R32, sum_ + wo + 2048); \
    } while (0)

    const f32x4 z4 = {0.f, 0.f, 0.f, 0.f};
    f32x4 accg[2][2], accu[2][2], accgX[2][2], accuX[2][2];
    double accgD[2][2][4], accuD[2][2][4];
    #pragma unroll
    for (int i = 0; i < 2; ++i)
        #pragma unroll
        for (int j = 0; j < 2; ++j) {
            accg[i][j] = z4; accu[i][j] = z4; accgX[i][j] = z4; accuX[i][j] = z4;
            #pragma unroll
            for (int r = 0; r < 4; ++r) { accgD[i][j][r] = 0.0; accuD[i][j][r] = 0.0; }
        }

    const int frow = lane & 15;
    const int l4 = lane >> 4;

    for (int t = 0; t < 64; ++t) {
        STAGE1(t << 6);
        __syncthreads();
        __builtin_amdgcn_s_setprio(1);
        #pragma unroll
        for (int kk = 0; kk < 2; ++kk) {
            const int ksl = (kk << 2) + l4;
            half8 ah[2], am2[2], bh[2], bm[2], ch[2], cm[2];
            #pragma unroll
            for (int i = 0; i < 2; ++i) {
                const int ra = wr * 32 + i * 16 + frow;
                const int so = (ksl ^ (ra & 7)) * 8;
                ah[i]  = *(const half8*)(sAh + ra * 64 + so);
                am2[i] = *(const half8*)(sAm + ra * 64 + so);
            }
            #pragma unroll
            for (int j = 0; j < 2; ++j) {
                const int rb = wc * 32 + j * 16 + frow;
                const int so = (ksl ^ (rb & 7)) * 8;
                bh[j] = *(const half8*)(sgh + rb * 64 + so);
                bm[j] = *(const half8*)(sgm + rb * 64 + so);
                ch[j] = *(const half8*)(suh + rb * 64 + so);
                cm[j] = *(const half8*)(sum_ + rb * 64 + so);
            }
            #pragma unroll
            for (int i = 0; i < 2; ++i)
                #pragma unroll
                for (int j = 0; j < 2; ++j) {
                    accg[i][j]  = __builtin_amdgcn_mfma_f32_16x16x32_f16(ah[i],  bh[j], accg[i][j], 0, 0, 0);
                    accgX[i][j] = __builtin_amdgcn_mfma_f32_16x16x32_f16(ah[i],  bm[j], accgX[i][j], 0, 0, 0);
                    accgX[i][j] = __builtin_amdgcn_mfma_f32_16x16x32_f16(am2[i], bh[j], accgX[i][j], 0, 0, 0);
                    accu[i][j]  = __builtin_amdgcn_mfma_f32_16x16x32_f16(ah[i],  ch[j], accu[i][j], 0, 0, 0);
                    accuX[i][j] = __builtin_amdgcn_mfma_f32_16x16x32_f16(ah[i],  cm[j], accuX[i][j], 0, 0, 0);
                    accuX[i][j] = __builtin_amdgcn_mfma_f32_16x16x32_f16(am2[i], ch[j], accuX[i][j], 0, 0, 0);
                }
        }
        __builtin_amdgcn_s_setprio(0);
        if ((t & 7) == 7) {   // flush every K=512 (cadence identical to green rounds)
            #pragma unroll
            for (int i = 0; i < 2; ++i)
                #pragma unroll
                for (int j = 0; j < 2; ++j) {
                    #pragma unroll
                    for (int r = 0; r < 4; ++r) {
                        accgD[i][j][r] += (double)accg[i][j][r];
                        accuD[i][j][r] += (double)accu[i][j][r];
                    }
                    accg[i][j] = z4; accu[i][j] = z4;
                }
        }
        __syncthreads();
    }
#undef STAGE1

    double lmax = 0.0;
    const int crow = l4 * 4, ccol = lane & 15;
    #pragma unroll
    for (int i = 0; i < 2; ++i) {
        #pragma unroll
        for (int j = 0; j < 2; ++j) {
            const int row = hrow0 + arow0 + wr * 32 + i * 16 + crow;
            const int col = hcol0 + brow0 + wc * 32 + j * 16 + ccol;
            #pragma unroll
            for (int r = 0; r < 4; ++r) {
                double g = accgD[i][j][r] + (double)accgX[i][j][r] * 0x1p-12;
                double u = accuD[i][j][r] + (double)accuX[i][j][r] * 0x1p-12;
                double sig = 1.0 / (1.0 + exp(-g));
                double h = (g * sig) * u;
                lmax = fmax(lmax, fabs(h));
                H[(long)(row + r) * 11008 + col] = (float)h;
            }
        }
    }
    #pragma unroll
    for (int off = 32; off > 0; off >>= 1) lmax = fmax(lmax, __shfl_down(lmax, off));
    if (lane == 0) atomicMax(hmax64, (unsigned long long)__double_as_longlong(lmax));
}

// ---------------------------------------------------------------- GEMM 2
// fp16, 128x128 tile, BK=128, 16-slot row swizzle (proven ~790us, at its
// staging-volume roofline); out = (Hq @ Wd^T)*scale + T1 @ lrB

__global__ __launch_bounds__(256, 2)
void gemm2_kernel(const _Float16* __restrict__ A,    // hq  [8192][11008]
                  const _Float16* __restrict__ B,    // wdq [4096][11008]
                  const float* __restrict__ scale,   // [4096]
                  const _Float16* __restrict__ T1,   // [8192][64]
                  const _Float16* __restrict__ BT,   // lrBT [4096][64]
                  float* __restrict__ out) {
    __shared__ __align__(16) _Float16 sA[128 * 128];   // 32 KB
    __shared__ __align__(16) _Float16 sB[128 * 128];   // 32 KB
    const int tid = threadIdx.x;
    const int lane = tid & 63, wave = tid >> 6;
    const int wr = wave >> 1, wc = wave & 1;
    const int arow0 = blockIdx.x * 128, brow0 = blockIdx.y * 128;

    const int qrow = tid >> 4, qsl = tid & 15;
    const int qslx = qsl ^ (qrow & 15);
    const _Float16* gA = A + (long)(arow0 + qrow) * 11008 + qslx * 8;
    const _Float16* gB = B + (long)(brow0 + qrow) * 11008 + qslx * 8;
    const long QROW16 = 16L * 11008;

    const f32x4 z4 = {0.f, 0.f, 0.f, 0.f};
    f32x4 acc[4][4];
    #pragma unroll
    for (int i = 0; i < 4; ++i)
        #pragma unroll
        for (int j = 0; j < 4; ++j) acc[i][j] = z4;

    const int frow = lane & 15;
    const int l4 = lane >> 4;

    for (int k0 = 0; k0 < 11008; k0 += 128) {
        #pragma unroll
        for (int q = 0; q < 8; ++q) {
            g2l16(gA + k0 + q * QROW16, sA + q * 2048 + wave * 512);
            g2l16(gB + k0 + q * QROW16, sB + q * 2048 + wave * 512);
        }
        __syncthreads();
        #pragma unroll
        for (int kk = 0; kk < 4; ++kk) {
            const int ksl = (kk << 2) + l4;
            half8 af[4], bf[4];
            #pragma unroll
            for (int i = 0; i < 4; ++i) {
                const int ra = wr * 64 + i * 16 + frow;
                af[i] = *(const half8*)(sA + ra * 128 + ((ksl ^ (ra & 15)) * 8));
            }
            #pragma unroll
            for (int j = 0; j < 4; ++j) {
                const int rb = wc * 64 + j * 16 + frow;
                bf[j] = *(const half8*)(sB + rb * 128 + ((ksl ^ (rb & 15)) * 8));
            }
            #pragma unroll
            for (int i = 0; i < 4; ++i)
                #pragma unroll
                for (int j = 0; j < 4; ++j)
                    acc[i][j] = __builtin_amdgcn_mfma_f32_16x16x32_f16(af[i], bf[j], acc[i][j], 0, 0, 0);
        }
        __syncthreads();
    }

    // rank-64 low-rank tail (separate accumulator; scale must not apply to it)
    f32x4 accL[4][4];
    #pragma unroll
    for (int i = 0; i < 4; ++i)
        #pragma unroll
        for (int j = 0; j < 4; ++j) accL[i][j] = z4;
    const int r8 = tid >> 3, sl8 = tid & 7;
    const int slx8 = sl8 ^ (r8 & 7);
    const _Float16* gT = T1 + (long)(arow0 + r8) * 64 + slx8 * 8;
    const _Float16* gL = BT + (long)(brow0 + r8) * 64 + slx8 * 8;
    #pragma unroll
    for (int q = 0; q < 4; ++q) {
        g2l16(gT + q * (32L * 64), sA + q * 2048 + wave * 512);
        g2l16(gL + q * (32L * 64), sB + q * 2048 + wave * 512);
    }
    __syncthreads();
    #pragma unroll
    for (int kk = 0; kk < 2; ++kk) {
        const int ksl = (kk << 2) + l4;
        half8 af[4], bf[4];
        #pragma unroll
        for (int i = 0; i < 4; ++i) {
            const int ra = wr * 64 + i * 16 + frow;
            af[i] = *(const half8*)(sA + ra * 64 + (ksl ^ (ra & 7)) * 8);
        }
        #pragma unroll
        for (int j = 0; j < 4; ++j) {
            const int rb = wc * 64 + j * 16 + frow;
            bf[j] = *(const half8*)(sB + rb * 64 + (ksl ^ (rb & 7)) * 8);
        }
        #pragma unroll
        for (int i = 0; i < 4; ++i)
            #pragma unroll
            for (int j = 0; j < 4; ++j)
                accL[i][j] = __builtin_amdgcn_mfma_f32_16x16x32_f16(af[i], bf[j], accL[i][j], 0, 0, 0);
    }

    const int crow = l4 * 4, ccol = lane & 15;
    #pragma unroll
    for (int j = 0; j < 4; ++j) {
        const int col = brow0 + wc * 64 + j * 16 + ccol;
        const float sc = scale[col];
        #pragma unroll
        for (int i = 0; i < 4; ++i) {
            const int row = arow0 + wr * 64 + i * 16 + crow;
            #pragma unroll
            for (int r = 0; r < 4; ++r)
                out[(long)(row + r) * 4096 + col] = acc[i][j][r] * sc + accL[i][j][r];
        }
    }
}

// T1 = xh @ lrA  (M=8192, N=64, K=4096), fp16. (tiny; unchanged)
__global__ __launch_bounds__(256, 2)
void lr1_kernel(const _Float16* __restrict__ X,
                const _Float16* __restrict__ AT,
                _Float16* __restrict__ T1) {
    __shared__ __align__(16) _Float16 sA[128 * 32];
    __shared__ __align__(16) _Float16 sB[64 * 32];
    const int tid = threadIdx.x;
    const int lane = tid & 63, wave = tid >> 6;
    const int arow0 = blockIdx.x * 128;

    const int rs = tid >> 2, cs8 = (tid & 3) * 8;
    const _Float16* gA = X + (long)(arow0 + rs) * 4096 + cs8;
    const _Float16* gB = AT + (long)rs * 4096 + cs8;
    _Float16* lA = sA + wave * 512;
    _Float16* lB = sB + wave * 512;

    const f32x4 z4 = {0.f, 0.f, 0.f, 0.f};
    f32x4 acc[2][4];
    #pragma unroll
    for (int i = 0; i < 2; ++i)
        #pragma unroll
        for (int j = 0; j < 4; ++j) acc[i][j] = z4;

    const int frow = lane & 15;
    const int fke = (lane >> 4) * 8;

    for (int k0 = 0; k0 < 4096; k0 += 32) {
        g2l16(gA + k0,             lA);
        g2l16(gA + k0 + 64 * 4096, lA + 2048);
        g2l16(gB + k0, lB);
        __syncthreads();
        half8 af[2], bf[4];
        #pragma unroll
        for (int i = 0; i < 2; ++i)
            af[i] = *(const half8*)(sA + (wave * 32 + i * 16 + frow) * 32 + fke);
        #pragma unroll
        for (int j = 0; j < 4; ++j)
            bf[j] = *(const half8*)(sB + (j * 16 + frow) * 32 + fke);
        #pragma unroll
        for (int i = 0; i < 2; ++i)
            #pragma unroll
            for (int j = 0; j < 4; ++j)
                acc[i][j] = __builtin_amdgcn_mfma_f32_16x16x32_f16(af[i], bf[j], acc[i][j], 0, 0, 0);
        __syncthreads();
    }

    const int crow = (lane >> 4) * 4, ccol = lane & 15;
    #pragma unroll
    for (int i = 0; i < 2; ++i)
        #pragma unroll
        for (int j = 0; j < 4; ++j) {
            const int row = arow0 + wave * 32 + i * 16 + crow;
            const int col = j * 16 + ccol;
            #pragma unroll
            for (int r = 0; r < 4; ++r)
                T1[(long)(row + r) * 64 + col] = (_Float16)acc[i][j][r];
        }
}

// ---------------------------------------------------------------- launch

extern "C" void kernel_launch(void* const* d_in, const int* in_sizes, int n_in,
                              void* d_out, int out_size, void* d_ws, size_t ws_size,
                              hipStream_t stream) {
    const float* x     = (const float*)d_in[0];
    const float* wg    = (const float*)d_in[1];
    const float* wu    = (const float*)d_in[2];
    const float* wd    = (const float*)d_in[3];
    const float* scale = (const float*)d_in[4];
    const float* lrA   = (const float*)d_in[5];
    const float* lrB   = (const float*)d_in[6];
    const int* upidx   = (const int*)d_in[7];
    const int* dnidx   = (const int*)d_in[8];
    float* out = (float*)d_out;
    char* ws = (char*)d_ws;

    // FALLBACK (proven r13): m-chunks 2048, f-chunks 1024. 427,819,264 B.
    const long F_XQH = 256;
    const long F_XQM = F_XQH + 16777216L;
    const long F_WGH = F_XQM + 16777216L;
    const long F_WGM = F_WGH + 8388608L;
    const long F_WUH = F_WGM + 8388608L;
    const long F_WUM = F_WUH + 8388608L;
    const long F_H   = F_WUM + 8388608L;
    const long NEED_FB = F_H + 360710144L;

    // BIG (proven r14): m-chunks 4096, f-chunks 2048. 494,928,128 B.
    const long B_XQH = 256;
    const long B_XQM = B_XQH + 33554432L;
    const long B_WGH = B_XQM + 33554432L;
    const long B_WGM = B_WGH + 16777216L;
    const long B_WUH = B_WGM + 16777216L;
    const long B_WUM = B_WUH + 16777216L;
    const long B_H   = B_WUM + 16777216L;
    const long NEED_BIG = B_H + 360710144L;

    // HUGE (proven r15/16): full 8192-row xq, f-chunks 2048. 562,036,992 B.
    const long G_XQH = 256;
    const long G_XQM = G_XQH + 67108864L;
    const long G_WGH = G_XQM + 67108864L;
    const long G_WGM = G_WGH + 16777216L;
    const long G_WUH = G_WGM + 16777216L;
    const long G_WUM = G_WUH + 16777216L;
    const long G_H   = G_WUM + 16777216L;
    const long NEED_HUGE = G_H + 360710144L;

    if (ws_size < (size_t)NEED_FB) { sentinel_kernel<<<1, 1, 0, stream>>>(out); return; }
    const int TIER = (ws_size >= (size_t)NEED_HUGE) ? 2
                   : (ws_size >= (size_t)NEED_BIG) ? 1 : 0;

    const long OFF_H = (TIER == 2) ? G_H : (TIER == 1) ? B_H : F_H;
    const long OFF_HQ   = OFF_H + 180355072L;
    const long OFF_WDQ  = OFF_H;
    const long OFF_XH   = OFF_H + 90177536L;
    const long OFF_T1   = OFF_XH + 67108864L;
    const long OFF_LRAT = OFF_T1 + 1048576L;
    const long OFF_LRBT = OFF_LRAT + 524288L;

    unsigned* sc = (unsigned*)ws;
    unsigned long long* hmax64 = (unsigned long long*)(ws + 32);
    _Float16* xqh = (_Float16*)(ws + ((TIER == 2) ? G_XQH : (TIER == 1) ? B_XQH : F_XQH));
    _Float16* xqm = (_Float16*)(ws + ((TIER == 2) ? G_XQM : (TIER == 1) ? B_XQM : F_XQM));
    _Float16* wgh = (_Float16*)(ws + ((TIER == 2) ? G_WGH : (TIER == 1) ? B_WGH : F_WGH));
    _Float16* wgm = (_Float16*)(ws + ((TIER == 2) ? G_WGM : (TIER == 1) ? B_WGM : F_WGM));
    _Float16* wuh = (_Float16*)(ws + ((TIER == 2) ? G_WUH : (TIER == 1) ? B_WUH : F_WUH));
    _Float16* wum = (_Float16*)(ws + ((TIER == 2) ? G_WUM : (TIER == 1) ? B_WUM : F_WUM));
    float*    H   = (float*)(ws + OFF_H);
    _Float16* hq  = (TIER == 2) ? (_Float16*)(ws + G_XQH) : (_Float16*)(ws + OFF_HQ);
    _Float16* wdq = (_Float16*)(ws + OFF_WDQ);
    _Float16* xh  = (_Float16*)(ws + OFF_XH);
    _Float16* t1  = (_Float16*)(ws + OFF_T1);
    _Float16* lrAT = (_Float16*)(ws + OFF_LRAT);
    _Float16* lrBT = (_Float16*)(ws + OFF_LRBT);

    init_kernel<<<1, 64, 0, stream>>>(sc);
    absmax4_kernel<<<dim3(1024, 4), 256, 0, stream>>>(x, wg, wu, wd, sc + 0);

    if (TIER == 2) {
        quant_split16_kernel<<<8192, 256, 0, stream>>>(x, 4096, 256, 248,
                                                       upidx, sc + 0, xqh, xqm);
        for (int c = 0; c < 6; ++c) {
            const int frow0 = c * 2048;
            const int nrows = (frow0 + 2048 <= 11008) ? 2048 : (11008 - frow0);
            quant_wgu_kernel<<<2 * nrows, 256, 0, stream>>>(
                wg + (long)frow0 * 4096, wu + (long)frow0 * 4096, nrows,
                upidx, sc + 1, sc + 2, wgh, wgm, wuh, wum);
            gemm1_kernel<<<dim3(128, nrows / 64), 256, 0, stream>>>(
                xqh, xqm, wgh, wgm, wuh, wum, H, 0, frow0, hmax64);
        }
        requant_h_direct_kernel<<<8192, 256, 0, stream>>>(H, hq, dnidx, hmax64);
    } else if (TIER == 1) {
        for (int m = 0; m < 2; ++m) {
            const long xrow0 = (long)m * 4096;
            quant_split16_kernel<<<4096, 256, 0, stream>>>(x + xrow0 * 4096, 4096, 256, 248,
                                                           upidx, sc + 0, xqh, xqm);
            for (int c = 0; c < 6; ++c) {
                const int frow0 = c * 2048;
                const int nrows = (frow0 + 2048 <= 11008) ? 2048 : (11008 - frow0);
                quant_wgu_kernel<<<2 * nrows, 256, 0, stream>>>(
                    wg + (long)frow0 * 4096, wu + (long)frow0 * 4096, nrows,
                    upidx, sc + 1, sc + 2, wgh, wgm, wuh, wum);
                gemm1_kernel<<<dim3(64, nrows / 64), 256, 0, stream>>>(
                    xqh, xqm, wgh, wgm, wuh, wum, H, (int)xrow0, frow0, hmax64);
            }
        }
        requant_h_kernel<<<1, 256, 0, stream>>>(H, 8191, dnidx, hmax64);
        for (int d = 1; d <= 13; ++d) {
            int L = 8192 - (1 << d);
            int n = 1 << (d - 1);
            requant_h_kernel<<<n, 256, 0, stream>>>(H, L, dnidx, hmax64);
        }
    } else {
        for (int m = 0; m < 4; ++m) {
            const long xrow0 = (long)m * 2048;
            quant_split16_kernel<<<2048, 256, 0, stream>>>(x + xrow0 * 4096, 4096, 256, 248,
                                                           upidx, sc + 0, xqh, xqm);
            for (int c = 0; c < 11; ++c) {
                const int frow0 = c * 1024;
                const int nrows = (frow0 + 1024 <= 11008) ? 1024 : (11008 - frow0);
                quant_wgu_kernel<<<2 * nrows, 256, 0, stream>>>(
                    wg + (long)frow0 * 4096, wu + (long)frow0 * 4096, nrows,
                    upidx, sc + 1, sc + 2, wgh, wgm, wuh, wum);
                gemm1_kernel<<<dim3(32, nrows / 64), 256, 0, stream>>>(
                    xqh, xqm, wgh, wgm, wuh, wum, H, (int)xrow0, frow0, hmax64);
            }
        }
        requant_h_kernel<<<1, 256, 0, stream>>>(H, 8191, dnidx, hmax64);
        for (int d = 1; d <= 13; ++d) {
            int L = 8192 - (1 << d);
            int n = 1 << (d - 1);
            requant_h_kernel<<<n, 256, 0, stream>>>(H, L, dnidx, hmax64);
        }
    }

    // late phase (overlays in H's dead region)
    convert_f16_kernel<<<2048, 256, 0, stream>>>(x, 33554432 / 4, xh);
    transpose_f16_kernel<<<(4096 * 64 + 255) / 256, 256, 0, stream>>>(lrA, 4096, 64, lrAT);
    transpose_f16_kernel<<<(64 * 4096 + 255) / 256, 256, 0, stream>>>(lrB, 64, 4096, lrBT);
    lr1_kernel<<<64, 256, 0, stream>>>(xh, lrAT, t1);
    quant_rows_kernel<<<4096, 256, 0, stream>>>(wd, 11008, 688, 680, dnidx, sc + 3, wdq);
    gemm2_kernel<<<dim3(64, 32), 256, 0, stream>>>(hq, wdq, scale, t1, lrBT, out);
}